// Round 1
// baseline (1145.332 us; speedup 1.0000x reference)
//
#include <hip/hip_runtime.h>

constexpr int Bn  = 8;
constexpr int Tn  = 2048;
constexpr int Dn  = 512;
constexpr int DKn = 128;
constexpr int TBn = 16;      // query rows per attention block
constexpr int WINn = 736;    // TBn + 2*360
constexpr int LDSS = 737;    // padded LDS stride for scores

// ---------------------------------------------------------------------------
// Kernel 1: q = x@Wq + bq, k = x@Wk + bk.  8 rows per block, 256 threads.
// Thread tid<128 computes q column tid; tid>=128 computes k column tid-128.
// ---------------------------------------------------------------------------
__global__ __launch_bounds__(256) void qk_proj_kernel(
    const float* __restrict__ x,
    const float* __restrict__ Wq, const float* __restrict__ bq,
    const float* __restrict__ Wk, const float* __restrict__ bk,
    float* __restrict__ q, float* __restrict__ k) {
  __shared__ float xs[8][Dn];
  const int tid = threadIdx.x;
  const int row0 = blockIdx.x * 8;

  const float4* xg = (const float4*)(x + (size_t)row0 * Dn);
  float4* xs4 = (float4*)&xs[0][0];
  for (int i = tid; i < 8 * Dn / 4; i += 256) xs4[i] = xg[i];
  __syncthreads();

  const int c = tid & 127;
  const float* W    = (tid < 128) ? Wq : Wk;
  const float* bias = (tid < 128) ? bq : bk;
  float* outp       = (tid < 128) ? q  : k;

  float acc[8] = {0.f,0.f,0.f,0.f,0.f,0.f,0.f,0.f};
  for (int d = 0; d < Dn; d += 4) {
    float w0 = W[(size_t)(d + 0) * DKn + c];
    float w1 = W[(size_t)(d + 1) * DKn + c];
    float w2 = W[(size_t)(d + 2) * DKn + c];
    float w3 = W[(size_t)(d + 3) * DKn + c];
#pragma unroll
    for (int r = 0; r < 8; ++r) {
      float4 xv = *(const float4*)&xs[r][d];
      acc[r] = fmaf(w0, xv.x, acc[r]);
      acc[r] = fmaf(w1, xv.y, acc[r]);
      acc[r] = fmaf(w2, xv.z, acc[r]);
      acc[r] = fmaf(w3, xv.w, acc[r]);
    }
  }
  const float bb = bias[c];
#pragma unroll
  for (int r = 0; r < 8; ++r)
    outp[(size_t)(row0 + r) * DKn + c] = acc[r] + bb;
}

// ---------------------------------------------------------------------------
// Kernel 2: banded multi-window attention.  One block = 16 query rows.
// acc_out[t,:] = (1/3) * sum_w softmax_w(scores)[t,:] @ x
// ---------------------------------------------------------------------------
__global__ __launch_bounds__(256) void attn_kernel(
    const float* __restrict__ q, const float* __restrict__ k,
    const float* __restrict__ x, float* __restrict__ accv) {
  __shared__ float sc[TBn][LDSS];
  __shared__ float qs[TBn][132];     // 128 + 4 pad
  __shared__ float mls[TBn][3][2];   // per row, per window: max, 1/sumexp

  const int tid = threadIdx.x;
  const int b  = blockIdx.x / (Tn / TBn);
  const int t0 = (blockIdx.x % (Tn / TBn)) * TBn;
  const int jlo = t0 - 360;          // window start (may be negative)

  // stage q rows
  const float* qb = q + ((size_t)b * Tn + t0) * DKn;
  for (int i = tid; i < TBn * (DKn / 4); i += 256) {
    int r = i >> 5;          // DKn/4 == 32
    int d4 = i & 31;
    *(float4*)&qs[r][d4 * 4] = *(const float4*)&qb[(size_t)r * DKn + d4 * 4];
  }
  __syncthreads();

  // Phase A: scores for all (r, jj) in the union window
  const float scale = 0.08838834764831845f;   // 1/sqrt(128)
  for (int idx = tid; idx < TBn * WINn; idx += 256) {
    int r  = idx & 15;
    int jj = idx >> 4;
    int j  = jlo + jj;
    float s = -1e30f;
    if (j >= 0 && j < Tn) {
      const float* kp = k + ((size_t)b * Tn + j) * DKn;
      float a0 = 0.f, a1 = 0.f, a2 = 0.f, a3 = 0.f;
      for (int d = 0; d < DKn; d += 4) {
        float4 kv = *(const float4*)&kp[d];
        float4 qv = *(const float4*)&qs[r][d];
        a0 = fmaf(qv.x, kv.x, a0);
        a1 = fmaf(qv.y, kv.y, a1);
        a2 = fmaf(qv.z, kv.z, a2);
        a3 = fmaf(qv.w, kv.w, a3);
      }
      s = (a0 + a1 + a2 + a3) * scale;
    }
    sc[r][jj] = s;
  }
  __syncthreads();

  // Phase B: per-row, per-window max & sumexp (one wave handles rows wv,wv+4,..)
  const int wv = tid >> 6;
  const int lane = tid & 63;
  const int w2arr[3] = {12, 84, 360};
  for (int r = wv; r < TBn; r += 4) {
    const int center = r + 360;
#pragma unroll
    for (int w = 0; w < 3; ++w) {
      int lo = center - w2arr[w];
      int hi = center + w2arr[w];
      if (jlo < 0 && lo < -jlo) lo = -jlo;       // j >= 0
      int hmax = Tn - 1 - jlo;                   // j <= T-1
      if (hi > hmax) hi = hmax;
      float m = -1e30f;
      for (int jj = lo + lane; jj <= hi; jj += 64) m = fmaxf(m, sc[r][jj]);
#pragma unroll
      for (int o = 32; o > 0; o >>= 1) m = fmaxf(m, __shfl_xor(m, o));
      float l = 0.f;
      for (int jj = lo + lane; jj <= hi; jj += 64) l += __expf(sc[r][jj] - m);
#pragma unroll
      for (int o = 32; o > 0; o >>= 1) l += __shfl_xor(l, o);
      if (lane == 0) { mls[r][w][0] = m; mls[r][w][1] = 1.f / l; }
    }
  }
  __syncthreads();

  // Phase B2: combined weights overwrite sc
  for (int idx = tid; idx < TBn * WINn; idx += 256) {
    int r  = idx & 15;
    int jj = idx >> 4;
    int j  = jlo + jj;
    float c = 0.f;
    if (j >= 0 && j < Tn) {
      float s = sc[r][jj];
      int dist = jj - (r + 360);
      dist = dist < 0 ? -dist : dist;
      if (dist <= 12)  c += __expf(s - mls[r][0][0]) * mls[r][0][1];
      if (dist <= 84)  c += __expf(s - mls[r][1][0]) * mls[r][1][1];
      if (dist <= 360) c += __expf(s - mls[r][2][0]) * mls[r][2][1];
    }
    sc[r][jj] = c * (1.f / 3.f);
  }
  __syncthreads();

  // Phase C: PV.  Group g (16 lanes) owns row g; each lane owns 8 float4 of D.
  const int g   = tid >> 4;
  const int l16 = tid & 15;
  const float* xb = x + (size_t)b * Tn * Dn;
  float4 a4[8];
#pragma unroll
  for (int m = 0; m < 8; ++m) a4[m] = make_float4(0.f, 0.f, 0.f, 0.f);
  int jjlo = g, jjhi = g + 720;
  if (jlo < 0 && jjlo < -jlo) jjlo = -jlo;
  { int hmax = Tn - 1 - jlo; if (jjhi > hmax) jjhi = hmax; }
  for (int jj = jjlo; jj <= jjhi; ++jj) {
    float c = sc[g][jj];
    const float4* xr = (const float4*)&xb[(size_t)(jlo + jj) * Dn];
#pragma unroll
    for (int m = 0; m < 8; ++m) {
      float4 xv = xr[l16 + 16 * m];
      a4[m].x = fmaf(c, xv.x, a4[m].x);
      a4[m].y = fmaf(c, xv.y, a4[m].y);
      a4[m].z = fmaf(c, xv.z, a4[m].z);
      a4[m].w = fmaf(c, xv.w, a4[m].w);
    }
  }
  float4* ob = (float4*)(accv + ((size_t)b * Tn + t0 + g) * Dn);
#pragma unroll
  for (int m = 0; m < 8; ++m) ob[l16 + 16 * m] = a4[m];
}

// ---------------------------------------------------------------------------
// Kernel 3: out = acc@Wo + bo; res = x + out; LayerNorm(res).
// 8 rows per block; thread owns output cols tid and tid+256.
// ---------------------------------------------------------------------------
__global__ __launch_bounds__(256) void out_ln_kernel(
    const float* __restrict__ accv, const float* __restrict__ x,
    const float* __restrict__ Wo, const float* __restrict__ bo,
    const float* __restrict__ gamma, const float* __restrict__ beta,
    float* __restrict__ out) {
  __shared__ float as[8][Dn];
  __shared__ float red[8][2][4];
  const int tid = threadIdx.x;
  const int row0 = blockIdx.x * 8;

  const float4* ag = (const float4*)(accv + (size_t)row0 * Dn);
  float4* as4 = (float4*)&as[0][0];
  for (int i = tid; i < 8 * Dn / 4; i += 256) as4[i] = ag[i];
  __syncthreads();

  const int o0 = tid, o1 = tid + 256;
  float acc0[8] = {0.f,0.f,0.f,0.f,0.f,0.f,0.f,0.f};
  float acc1[8] = {0.f,0.f,0.f,0.f,0.f,0.f,0.f,0.f};
  for (int d = 0; d < Dn; d += 4) {
    float wa0 = Wo[(size_t)(d + 0) * Dn + o0];
    float wa1 = Wo[(size_t)(d + 1) * Dn + o0];
    float wa2 = Wo[(size_t)(d + 2) * Dn + o0];
    float wa3 = Wo[(size_t)(d + 3) * Dn + o0];
    float wb0 = Wo[(size_t)(d + 0) * Dn + o1];
    float wb1 = Wo[(size_t)(d + 1) * Dn + o1];
    float wb2 = Wo[(size_t)(d + 2) * Dn + o1];
    float wb3 = Wo[(size_t)(d + 3) * Dn + o1];
#pragma unroll
    for (int r = 0; r < 8; ++r) {
      float4 xv = *(const float4*)&as[r][d];
      acc0[r] = fmaf(wa0, xv.x, acc0[r]);
      acc0[r] = fmaf(wa1, xv.y, acc0[r]);
      acc0[r] = fmaf(wa2, xv.z, acc0[r]);
      acc0[r] = fmaf(wa3, xv.w, acc0[r]);
      acc1[r] = fmaf(wb0, xv.x, acc1[r]);
      acc1[r] = fmaf(wb1, xv.y, acc1[r]);
      acc1[r] = fmaf(wb2, xv.z, acc1[r]);
      acc1[r] = fmaf(wb3, xv.w, acc1[r]);
    }
  }

  const float bo0 = bo[o0], bo1 = bo[o1];
  const float* xb = x + (size_t)row0 * Dn;
  float r0[8], r1[8];
#pragma unroll
  for (int r = 0; r < 8; ++r) {
    r0[r] = acc0[r] + bo0 + xb[(size_t)r * Dn + o0];
    r1[r] = acc1[r] + bo1 + xb[(size_t)r * Dn + o1];
  }

  const int wv = tid >> 6, lane = tid & 63;
#pragma unroll
  for (int r = 0; r < 8; ++r) {
    float s  = r0[r] + r1[r];
    float s2 = r0[r] * r0[r] + r1[r] * r1[r];
#pragma unroll
    for (int o = 32; o > 0; o >>= 1) {
      s  += __shfl_xor(s, o);
      s2 += __shfl_xor(s2, o);
    }
    if (lane == 0) { red[r][0][wv] = s; red[r][1][wv] = s2; }
  }
  __syncthreads();

  const float g0 = gamma[o0], g1 = gamma[o1];
  const float be0 = beta[o0], be1 = beta[o1];
#pragma unroll
  for (int r = 0; r < 8; ++r) {
    float s  = red[r][0][0] + red[r][0][1] + red[r][0][2] + red[r][0][3];
    float s2 = red[r][1][0] + red[r][1][1] + red[r][1][2] + red[r][1][3];
    float mean = s * (1.f / 512.f);
    float var  = s2 * (1.f / 512.f) - mean * mean;
    float inv  = rsqrtf(var + 1e-5f);
    out[(size_t)(row0 + r) * Dn + o0] = (r0[r] - mean) * inv * g0 + be0;
    out[(size_t)(row0 + r) * Dn + o1] = (r1[r] - mean) * inv * g1 + be1;
  }
}

// ---------------------------------------------------------------------------
extern "C" void kernel_launch(void* const* d_in, const int* in_sizes, int n_in,
                              void* d_out, int out_size, void* d_ws, size_t ws_size,
                              hipStream_t stream) {
  const float* x     = (const float*)d_in[0];
  const float* Wq    = (const float*)d_in[1];
  const float* bq    = (const float*)d_in[2];
  const float* Wk    = (const float*)d_in[3];
  const float* bk    = (const float*)d_in[4];
  const float* Wo    = (const float*)d_in[5];
  const float* bo    = (const float*)d_in[6];
  const float* gamma = (const float*)d_in[7];
  const float* beta  = (const float*)d_in[8];
  float* out = (float*)d_out;

  // workspace layout: q [B*T*DK] | k [B*T*DK] | acc [B*T*D]   (all f32)
  float* qd  = (float*)d_ws;
  float* kd  = qd + (size_t)Bn * Tn * DKn;
  float* acc = kd + (size_t)Bn * Tn * DKn;

  qk_proj_kernel<<<Bn * Tn / 8, 256, 0, stream>>>(x, Wq, bq, Wk, bk, qd, kd);
  attn_kernel<<<Bn * (Tn / TBn), 256, 0, stream>>>(qd, kd, x, acc);
  out_ln_kernel<<<Bn * Tn / 8, 256, 0, stream>>>(acc, x, Wo, bo, gamma, beta, out);
}

// Round 2
// 358.883 us; speedup vs baseline: 3.1914x; 3.1914x over previous
//
#include <hip/hip_runtime.h>

typedef unsigned short u16;
typedef __attribute__((ext_vector_type(8))) unsigned short u16x8;
typedef __attribute__((ext_vector_type(8))) short bf16x8;
typedef __attribute__((ext_vector_type(4))) float f32x4;

constexpr int Bn = 8, Tn = 2048, Dn = 512, DKn = 128;
constexpr int QB = 64;      // query rows per block (weights & pv)
constexpr int WJ = 832;     // padded union window = 13*64
constexpr int NCH = 13;     // K-chunks of 64
constexpr int SST = 833;    // S LDS stride (u16 elems)

__device__ inline u16 f2bf(float f) {
  unsigned u = __float_as_uint(f);
  return (u16)((u + 0x7FFFu + ((u >> 16) & 1u)) >> 16);
}
__device__ inline float bf2f(u16 h) {
  return __uint_as_float(((unsigned)h) << 16);
}
__device__ inline void gload16(const void* g, void* l) {
  __builtin_amdgcn_global_load_lds(
      (const __attribute__((address_space(1))) unsigned int*)g,
      (__attribute__((address_space(3))) unsigned int*)l, 16, 0, 0);
}
__device__ inline f32x4 mfma16(bf16x8 a, bf16x8 b, f32x4 c) {
  return __builtin_amdgcn_mfma_f32_16x16x32_bf16(a, b, c, 0, 0, 0);
}

// ---------------------------------------------------------------------------
// Kernel 1: q = x@Wq + bq, k = x@Wk + bk -> bf16 outputs (row-major).
// ---------------------------------------------------------------------------
__global__ __launch_bounds__(256) void qk_proj_kernel(
    const float* __restrict__ x,
    const float* __restrict__ Wq, const float* __restrict__ bq,
    const float* __restrict__ Wk, const float* __restrict__ bk,
    u16* __restrict__ qbf, u16* __restrict__ kbf) {
  __shared__ float xs[8][Dn];
  const int tid = threadIdx.x;
  const int row0 = blockIdx.x * 8;

  const float4* xg = (const float4*)(x + (size_t)row0 * Dn);
  float4* xs4 = (float4*)&xs[0][0];
  for (int i = tid; i < 8 * Dn / 4; i += 256) xs4[i] = xg[i];
  __syncthreads();

  const int c = tid & 127;
  const float* W    = (tid < 128) ? Wq : Wk;
  const float* bias = (tid < 128) ? bq : bk;
  u16* outp         = (tid < 128) ? qbf : kbf;

  float acc[8] = {0.f,0.f,0.f,0.f,0.f,0.f,0.f,0.f};
  for (int d = 0; d < Dn; d += 4) {
    float w0 = W[(size_t)(d + 0) * DKn + c];
    float w1 = W[(size_t)(d + 1) * DKn + c];
    float w2 = W[(size_t)(d + 2) * DKn + c];
    float w3 = W[(size_t)(d + 3) * DKn + c];
#pragma unroll
    for (int r = 0; r < 8; ++r) {
      float4 xv = *(const float4*)&xs[r][d];
      acc[r] = fmaf(w0, xv.x, acc[r]);
      acc[r] = fmaf(w1, xv.y, acc[r]);
      acc[r] = fmaf(w2, xv.z, acc[r]);
      acc[r] = fmaf(w3, xv.w, acc[r]);
    }
  }
  const float bb = bias[c];
#pragma unroll
  for (int r = 0; r < 8; ++r)
    outp[(size_t)(row0 + r) * DKn + c] = f2bf(acc[r] + bb);
}

// ---------------------------------------------------------------------------
// Kernel 2: xT[b][d][t] = bf16(x[b][t][d]).  64x64 tiles via LDS.
// ---------------------------------------------------------------------------
__global__ __launch_bounds__(256) void xpose_kernel(
    const float* __restrict__ x, u16* __restrict__ xT) {
  __shared__ u16 tile[64][72];
  const int blk = blockIdx.x;
  const int b = blk >> 8;                 // 256 tiles per batch
  const int rem = blk & 255;
  const int t0 = (rem >> 3) * 64, d0 = (rem & 7) * 64;
  const int tid = threadIdx.x;

#pragma unroll
  for (int it = 0; it < 4; ++it) {
    int r = (tid >> 4) + it * 16;
    int c = (tid & 15) * 4;
    float4 v = *(const float4*)&x[(size_t)(b * Tn + t0 + r) * Dn + d0 + c];
    tile[c + 0][r] = f2bf(v.x);
    tile[c + 1][r] = f2bf(v.y);
    tile[c + 2][r] = f2bf(v.z);
    tile[c + 3][r] = f2bf(v.w);
  }
  __syncthreads();
  const int dr = tid >> 2, ts = (tid & 3) * 16;
  u16x8 v0 = *(const u16x8*)&tile[dr][ts];
  u16x8 v1 = *(const u16x8*)&tile[dr][ts + 8];
  u16* dst = xT + (size_t)(b * Dn + d0 + dr) * Tn + t0 + ts;
  *(u16x8*)dst = v0;
  *(u16x8*)(dst + 8) = v1;
}

// ---------------------------------------------------------------------------
// Kernel 3: banded scores via MFMA + 3-window softmax -> combined weights.
// Block = 64 query rows.  Wg[blk][64][832] bf16 (zeros outside band/valid).
// ---------------------------------------------------------------------------
__global__ __launch_bounds__(512) void weights_kernel(
    const u16* __restrict__ qbf, const u16* __restrict__ kbf,
    u16* __restrict__ Wg) {
  __shared__ u16 qs[QB * DKn];        // 16 KB, src-swizzled 16-slot rows
  __shared__ u16 ks[2][QB * DKn];     // 2 x 16 KB
  __shared__ u16 S[QB * SST];         // ~104 KB bf16 scores
  const int tid = threadIdx.x;
  const int w = tid >> 6, l = tid & 63;
  const int blk = blockIdx.x;
  const int b = blk >> 5;
  const int t064 = (blk & 31) * QB;
  const int jbase = t064 - 360;

  // stage q (pre-swizzled global source, linear LDS dest)
#pragma unroll
  for (int ii = 0; ii < 2; ++ii) {
    int i = 2 * w + ii;
    int row = i * 4 + (l >> 4);
    int ss = (l & 15) ^ (row & 15);
    gload16(qbf + ((size_t)(b * Tn + t064 + row) * DKn + ss * 8),
            (char*)qs + i * 1024);
  }
  // stage k chunk 0
#pragma unroll
  for (int ii = 0; ii < 2; ++ii) {
    int i = 2 * w + ii;
    int row = i * 4 + (l >> 4);
    int j = jbase + row; j = j < 0 ? 0 : (j > Tn - 1 ? Tn - 1 : j);
    int ss = (l & 15) ^ (row & 15);
    gload16(kbf + ((size_t)(b * Tn + j) * DKn + ss * 8),
            (char*)&ks[0][0] + i * 1024);
  }
  __syncthreads();

  const int mw = w >> 1, nh = w & 1;
  const int rA = mw * 16 + (l & 15);
  const float scale = 0.08838834764831845f;   // 1/sqrt(128)

  for (int c = 0; c < NCH; ++c) {
    if (c + 1 < NCH) {
#pragma unroll
      for (int ii = 0; ii < 2; ++ii) {
        int i = 2 * w + ii;
        int row = i * 4 + (l >> 4);
        int j = jbase + (c + 1) * 64 + row;
        j = j < 0 ? 0 : (j > Tn - 1 ? Tn - 1 : j);
        int ss = (l & 15) ^ (row & 15);
        gload16(kbf + ((size_t)(b * Tn + j) * DKn + ss * 8),
                (char*)&ks[(c + 1) & 1][0] + i * 1024);
      }
    }
    const u16* kb = &ks[c & 1][0];
    f32x4 acc0 = {0.f,0.f,0.f,0.f}, acc1 = {0.f,0.f,0.f,0.f};
#pragma unroll
    for (int kk = 0; kk < 4; ++kk) {
      int sa = ((l >> 4) + 4 * kk) ^ (rA & 15);
      bf16x8 a = *(const bf16x8*)(qs + rA * DKn + sa * 8);
      int rB0 = nh * 32 + (l & 15);
      int sb0 = ((l >> 4) + 4 * kk) ^ (rB0 & 15);
      bf16x8 b0 = *(const bf16x8*)(kb + rB0 * DKn + sb0 * 8);
      int rB1 = rB0 + 16;
      int sb1 = ((l >> 4) + 4 * kk) ^ (rB1 & 15);
      bf16x8 b1 = *(const bf16x8*)(kb + rB1 * DKn + sb1 * 8);
      acc0 = mfma16(a, b0, acc0);
      acc1 = mfma16(a, b1, acc1);
    }
    int srow = mw * 16 + 4 * (l >> 4);
    int col0 = c * 64 + nh * 32 + (l & 15);
#pragma unroll
    for (int i = 0; i < 4; ++i) {
      S[(srow + i) * SST + col0]      = f2bf(acc0[i] * scale);
      S[(srow + i) * SST + col0 + 16] = f2bf(acc1[i] * scale);
    }
    __syncthreads();
  }

  // softmax stats + combined weights; 8 rows per wave
  const int jjminv = jbase < 0 ? -jbase : 0;
  int jjmaxv = (Tn - 1) - jbase; if (jjmaxv > WJ - 1) jjmaxv = WJ - 1;
  u16* wout = Wg + (size_t)blk * QB * WJ;
  for (int r = w * 8; r < w * 8 + 8; ++r) {
    const int center = r + 360;
    float m[3], il[3];
    const int hw[3] = {12, 84, 360};
#pragma unroll
    for (int wi = 0; wi < 3; ++wi) {
      int lo = center - hw[wi]; if (lo < jjminv) lo = jjminv;
      int hi = center + hw[wi]; if (hi > jjmaxv) hi = jjmaxv;
      float mm = -1e30f;
      for (int jj = lo + l; jj <= hi; jj += 64)
        mm = fmaxf(mm, bf2f(S[r * SST + jj]));
#pragma unroll
      for (int o = 32; o; o >>= 1) mm = fmaxf(mm, __shfl_xor(mm, o));
      float sum = 0.f;
      for (int jj = lo + l; jj <= hi; jj += 64)
        sum += __expf(bf2f(S[r * SST + jj]) - mm);
#pragma unroll
      for (int o = 32; o; o >>= 1) sum += __shfl_xor(sum, o);
      m[wi] = mm; il[wi] = 1.f / sum;
    }
    for (int jj = l; jj < WJ; jj += 64) {
      float cc = 0.f;
      if (jj >= jjminv && jj <= jjmaxv) {
        float s = bf2f(S[r * SST + jj]);
        int d = jj - center; d = d < 0 ? -d : d;
        if (d <= 12)  cc += __expf(s - m[0]) * il[0];
        if (d <= 84)  cc += __expf(s - m[1]) * il[1];
        if (d <= 360) cc += __expf(s - m[2]) * il[2];
      }
      wout[r * WJ + jj] = f2bf(cc * (1.f / 3.f));
    }
  }
}

// ---------------------------------------------------------------------------
// Kernel 4: PV GEMM.  OUT[64 x 512] = Wg[64 x 832] @ xwin[832 x 512], bf16
// MFMA, double-buffered LDS (KC=64), XOR-swizzled fragments.
// ---------------------------------------------------------------------------
__global__ __launch_bounds__(512) void pv_kernel(
    const u16* __restrict__ Wg, const u16* __restrict__ xT,
    u16* __restrict__ accbf) {
  __shared__ u16 xs[2][Dn * 64];   // 2 x 64 KB  (rows = d, 64 j per row)
  __shared__ u16 ws[2][QB * 64];   // 2 x 8 KB   (rows = q-row, 64 j per row)
  const int tid = threadIdx.x;
  const int w = tid >> 6, l = tid & 63;
  const int blk = blockIdx.x;
  const int b = blk >> 5;
  const int t064 = (blk & 31) * QB;
  const int jbase = t064 - 360;
  const int wr = w >> 2, wc = w & 3;   // wave tile: rows wr*32, cols wc*128

  f32x4 acc[2][8];
#pragma unroll
  for (int mm = 0; mm < 2; ++mm)
#pragma unroll
    for (int n = 0; n < 8; ++n) acc[mm][n] = (f32x4){0.f,0.f,0.f,0.f};

  auto stage = [&](int c, int buf) {
    for (int ii = 0; ii < 8; ++ii) {
      int i = 8 * w + ii;
      int d = i * 8 + (l >> 3);
      int ss = (l & 7) ^ (d & 7);
      int g = jbase + c * 64 + ss * 8;
      g = g < 0 ? 0 : (g > Tn - 8 ? Tn - 8 : g);
      gload16(xT + ((size_t)(b * Dn + d) * Tn + g),
              (char*)&xs[buf][0] + i * 1024);
    }
    int row = 8 * w + (l >> 3);
    int ss = (l & 7) ^ (row & 7);
    gload16(Wg + ((size_t)(blk * QB + row)) * WJ + c * 64 + ss * 8,
            (char*)&ws[buf][0] + w * 1024);
  };

  stage(0, 0);
  __syncthreads();
  for (int c = 0; c < NCH; ++c) {
    if (c + 1 < NCH) stage(c + 1, (c + 1) & 1);
    const u16* xb = &xs[c & 1][0];
    const u16* wb = &ws[c & 1][0];
#pragma unroll
    for (int kk = 0; kk < 2; ++kk) {
      int rA0 = wr * 32 + (l & 15);
      int sA = ((l >> 4) + 4 * kk) ^ (rA0 & 7);
      bf16x8 a0 = *(const bf16x8*)(wb + rA0 * 64 + sA * 8);
      bf16x8 a1 = *(const bf16x8*)(wb + (rA0 + 16) * 64 + sA * 8);
#pragma unroll
      for (int n = 0; n < 8; ++n) {
        int rB = wc * 128 + n * 16 + (l & 15);
        int sB = ((l >> 4) + 4 * kk) ^ (rB & 7);
        bf16x8 bv = *(const bf16x8*)(xb + rB * 64 + sB * 8);
        acc[0][n] = mfma16(a0, bv, acc[0][n]);
        acc[1][n] = mfma16(a1, bv, acc[1][n]);
      }
    }
    __syncthreads();
  }
#pragma unroll
  for (int mm = 0; mm < 2; ++mm)
#pragma unroll
    for (int n = 0; n < 8; ++n)
#pragma unroll
      for (int i = 0; i < 4; ++i) {
        int row = wr * 32 + mm * 16 + 4 * (l >> 4) + i;
        int col = wc * 128 + n * 16 + (l & 15);
        accbf[(size_t)(b * Tn + t064 + row) * Dn + col] = f2bf(acc[mm][n][i]);
      }
}

// ---------------------------------------------------------------------------
// Kernel 5: out = acc@Wo + bo; res = x + out; LayerNorm.
// ---------------------------------------------------------------------------
__global__ __launch_bounds__(256) void out_ln_kernel(
    const u16* __restrict__ accv, const float* __restrict__ x,
    const float* __restrict__ Wo, const float* __restrict__ bo,
    const float* __restrict__ gamma, const float* __restrict__ beta,
    float* __restrict__ out) {
  __shared__ float as[8][Dn];
  __shared__ float red[8][2][4];
  const int tid = threadIdx.x;
  const int row0 = blockIdx.x * 8;

  const u16* ag = accv + (size_t)row0 * Dn;
  for (int i = tid; i < 8 * Dn / 8; i += 256) {
    u16x8 v = *(const u16x8*)&ag[i * 8];
    float* dr = &as[i >> 6][(i & 63) * 8];
#pragma unroll
    for (int j = 0; j < 8; ++j) dr[j] = bf2f(v[j]);
  }
  __syncthreads();

  const int o0 = tid, o1 = tid + 256;
  float acc0[8] = {0.f,0.f,0.f,0.f,0.f,0.f,0.f,0.f};
  float acc1[8] = {0.f,0.f,0.f,0.f,0.f,0.f,0.f,0.f};
  for (int d = 0; d < Dn; d += 4) {
    float wa0 = Wo[(size_t)(d + 0) * Dn + o0];
    float wa1 = Wo[(size_t)(d + 1) * Dn + o0];
    float wa2 = Wo[(size_t)(d + 2) * Dn + o0];
    float wa3 = Wo[(size_t)(d + 3) * Dn + o0];
    float wb0 = Wo[(size_t)(d + 0) * Dn + o1];
    float wb1 = Wo[(size_t)(d + 1) * Dn + o1];
    float wb2 = Wo[(size_t)(d + 2) * Dn + o1];
    float wb3 = Wo[(size_t)(d + 3) * Dn + o1];
#pragma unroll
    for (int r = 0; r < 8; ++r) {
      float4 xv = *(const float4*)&as[r][d];
      acc0[r] = fmaf(wa0, xv.x, acc0[r]);
      acc0[r] = fmaf(wa1, xv.y, acc0[r]);
      acc0[r] = fmaf(wa2, xv.z, acc0[r]);
      acc0[r] = fmaf(wa3, xv.w, acc0[r]);
      acc1[r] = fmaf(wb0, xv.x, acc1[r]);
      acc1[r] = fmaf(wb1, xv.y, acc1[r]);
      acc1[r] = fmaf(wb2, xv.z, acc1[r]);
      acc1[r] = fmaf(wb3, xv.w, acc1[r]);
    }
  }

  const float bo0 = bo[o0], bo1 = bo[o1];
  const float* xb = x + (size_t)row0 * Dn;
  float r0[8], r1[8];
#pragma unroll
  for (int r = 0; r < 8; ++r) {
    r0[r] = acc0[r] + bo0 + xb[(size_t)r * Dn + o0];
    r1[r] = acc1[r] + bo1 + xb[(size_t)r * Dn + o1];
  }

  const int wv = tid >> 6, lane = tid & 63;
#pragma unroll
  for (int r = 0; r < 8; ++r) {
    float s  = r0[r] + r1[r];
    float s2 = r0[r] * r0[r] + r1[r] * r1[r];
#pragma unroll
    for (int o = 32; o > 0; o >>= 1) {
      s  += __shfl_xor(s, o);
      s2 += __shfl_xor(s2, o);
    }
    if (lane == 0) { red[r][0][wv] = s; red[r][1][wv] = s2; }
  }
  __syncthreads();

  const float g0 = gamma[o0], g1 = gamma[o1];
  const float be0 = beta[o0], be1 = beta[o1];
#pragma unroll
  for (int r = 0; r < 8; ++r) {
    float s  = red[r][0][0] + red[r][0][1] + red[r][0][2] + red[r][0][3];
    float s2 = red[r][1][0] + red[r][1][1] + red[r][1][2] + red[r][1][3];
    float mean = s * (1.f / 512.f);
    float var  = s2 * (1.f / 512.f) - mean * mean;
    float inv  = rsqrtf(var + 1e-5f);
    out[(size_t)(row0 + r) * Dn + o0] = (r0[r] - mean) * inv * g0 + be0;
    out[(size_t)(row0 + r) * Dn + o1] = (r1[r] - mean) * inv * g1 + be1;
  }
}

// ---------------------------------------------------------------------------
extern "C" void kernel_launch(void* const* d_in, const int* in_sizes, int n_in,
                              void* d_out, int out_size, void* d_ws, size_t ws_size,
                              hipStream_t stream) {
  const float* x     = (const float*)d_in[0];
  const float* Wq    = (const float*)d_in[1];
  const float* bq    = (const float*)d_in[2];
  const float* Wk    = (const float*)d_in[3];
  const float* bk    = (const float*)d_in[4];
  const float* Wo    = (const float*)d_in[5];
  const float* bo    = (const float*)d_in[6];
  const float* gamma = (const float*)d_in[7];
  const float* beta  = (const float*)d_in[8];
  float* out = (float*)d_out;

  // workspace (u16 elems): qbf 2M | kbf 2M | xT 8M | Wg 13.63M | accbf 8M
  u16* qbf   = (u16*)d_ws;
  u16* kbf   = qbf + (size_t)Bn * Tn * DKn;            // 2,097,152
  u16* xT    = kbf + (size_t)Bn * Tn * DKn;
  u16* Wg    = xT + (size_t)Bn * Dn * Tn;              // 8,388,608
  u16* accbf = Wg + (size_t)Bn * 32 * QB * WJ;         // 13,631,488

  qk_proj_kernel<<<Bn * Tn / 8, 256, 0, stream>>>(x, Wq, bq, Wk, bk, qbf, kbf);
  xpose_kernel<<<Bn * 256, 256, 0, stream>>>(x, xT);
  weights_kernel<<<Bn * 32, 512, 0, stream>>>(qbf, kbf, Wg);
  pv_kernel<<<Bn * 32, 512, 0, stream>>>(Wg, xT, accbf);
  out_ln_kernel<<<Bn * Tn / 8, 256, 0, stream>>>(accbf, x, Wo, bo, gamma, beta, out);
}

// Round 3
// 159.652 us; speedup vs baseline: 7.1739x; 2.2479x over previous
//
#include <hip/hip_runtime.h>

typedef unsigned short u16;
typedef __attribute__((ext_vector_type(4))) unsigned short u16x4;
typedef __attribute__((ext_vector_type(8))) unsigned short u16x8;
typedef __attribute__((ext_vector_type(8))) short bf16x8;
typedef __attribute__((ext_vector_type(4))) float f32x4;

constexpr int Bn = 8, Tn = 2048, Dn = 512, DKn = 128;
constexpr int QB = 64;      // query rows per block (weights & pv)
constexpr int WJ = 832;     // padded union window = 13*64
constexpr int NCH = 13;     // K-chunks of 64
constexpr int SST = 833;    // S LDS stride (u16 elems)

__device__ inline u16 f2bf(float f) {
  unsigned u = __float_as_uint(f);
  return (u16)((u + 0x7FFFu + ((u >> 16) & 1u)) >> 16);
}
__device__ inline float bf2f(u16 h) {
  return __uint_as_float(((unsigned)h) << 16);
}
__device__ inline void gload16(const void* g, void* l) {
  __builtin_amdgcn_global_load_lds(
      (const __attribute__((address_space(1))) unsigned int*)g,
      (__attribute__((address_space(3))) unsigned int*)l, 16, 0, 0);
}
__device__ inline f32x4 mfma16(bf16x8 a, bf16x8 b, f32x4 c) {
  return __builtin_amdgcn_mfma_f32_16x16x32_bf16(a, b, c, 0, 0, 0);
}

// ---------------------------------------------------------------------------
// Kernel 1: xT[b][d][t] = bf16(x[b][t][d]) AND xbf[b][t][d] = bf16(x[b][t][d]).
// ---------------------------------------------------------------------------
__global__ __launch_bounds__(256) void xpose_kernel(
    const float* __restrict__ x, u16* __restrict__ xT, u16* __restrict__ xbf) {
  __shared__ u16 tile[64][72];
  const int blk = blockIdx.x;
  const int b = blk >> 8;                 // 256 tiles per batch
  const int rem = blk & 255;
  const int t0 = (rem >> 3) * 64, d0 = (rem & 7) * 64;
  const int tid = threadIdx.x;

#pragma unroll
  for (int it = 0; it < 4; ++it) {
    int r = (tid >> 4) + it * 16;
    int c = (tid & 15) * 4;
    float4 v = *(const float4*)&x[(size_t)(b * Tn + t0 + r) * Dn + d0 + c];
    u16 b0 = f2bf(v.x), b1 = f2bf(v.y), b2 = f2bf(v.z), b3 = f2bf(v.w);
    tile[c + 0][r] = b0;
    tile[c + 1][r] = b1;
    tile[c + 2][r] = b2;
    tile[c + 3][r] = b3;
    u16x4 pv; pv[0] = b0; pv[1] = b1; pv[2] = b2; pv[3] = b3;
    *(u16x4*)&xbf[(size_t)(b * Tn + t0 + r) * Dn + d0 + c] = pv;
  }
  __syncthreads();
  const int dr = tid >> 2, ts = (tid & 3) * 16;
  u16x8 v0 = *(const u16x8*)&tile[dr][ts];
  u16x8 v1 = *(const u16x8*)&tile[dr][ts + 8];
  u16* dst = xT + (size_t)(b * Dn + d0 + dr) * Tn + t0 + ts;
  *(u16x8*)dst = v0;
  *(u16x8*)(dst + 8) = v1;
}

// ---------------------------------------------------------------------------
// Kernel 2: weight prep.  WqkT[n][d] = bf16(Wq|Wk[d][n]) (n<128 -> Wq),
//           WoT[n][d] = bf16(Wo[d][n]).
// ---------------------------------------------------------------------------
__global__ __launch_bounds__(256) void wprep_kernel(
    const float* __restrict__ Wq, const float* __restrict__ Wk,
    const float* __restrict__ Wo,
    u16* __restrict__ WqkT, u16* __restrict__ WoT) {
  __shared__ u16 tile[64][72];
  const int tid = threadIdx.x;
  const int blk = blockIdx.x;
  const float* src; u16* dst;
  int srcC, r0, c0, rowOff;
  if (blk < 32) {
    src = (blk < 16) ? Wq : Wk;
    rowOff = (blk < 16) ? 0 : 128;
    int t = blk & 15;
    r0 = (t >> 1) * 64; c0 = (t & 1) * 64;
    srcC = 128; dst = WqkT;
  } else {
    int t = blk - 32;
    src = Wo; rowOff = 0;
    r0 = (t >> 3) * 64; c0 = (t & 7) * 64;
    srcC = 512; dst = WoT;
  }
#pragma unroll
  for (int it = 0; it < 4; ++it) {
    int r = (tid >> 4) + it * 16;
    int c = (tid & 15) * 4;
    float4 v = *(const float4*)&src[(size_t)(r0 + r) * srcC + c0 + c];
    tile[c + 0][r] = f2bf(v.x);
    tile[c + 1][r] = f2bf(v.y);
    tile[c + 2][r] = f2bf(v.z);
    tile[c + 3][r] = f2bf(v.w);
  }
  __syncthreads();
  const int dr = tid >> 2, ts = (tid & 3) * 16;
  u16x8 v0 = *(const u16x8*)&tile[dr][ts];
  u16x8 v1 = *(const u16x8*)&tile[dr][ts + 8];
  u16* dp = dst + (size_t)(rowOff + c0 + dr) * 512 + r0 + ts;
  *(u16x8*)dp = v0;
  *(u16x8*)(dp + 8) = v1;
}

// ---------------------------------------------------------------------------
// Kernel 3: q|k = xbf @ WqkT^T + bias, MFMA.  Block = 64 rows x 256 cols.
// ---------------------------------------------------------------------------
__global__ __launch_bounds__(512) void qk_mfma_kernel(
    const u16* __restrict__ xbf, const u16* __restrict__ WqkT,
    const float* __restrict__ bq, const float* __restrict__ bk,
    u16* __restrict__ qbf, u16* __restrict__ kbf) {
  __shared__ u16 as_[2][64 * 64];     // 2 x 8 KB
  __shared__ u16 bs_[2][256 * 64];    // 2 x 32 KB
  const int tid = threadIdx.x, w = tid >> 6, l = tid & 63;
  const int r0 = blockIdx.x * 64;
  const int wr = w >> 2, wc = w & 3;  // wave tile: 32 rows x 64 cols

  f32x4 acc[2][4];
#pragma unroll
  for (int mm = 0; mm < 2; ++mm)
#pragma unroll
    for (int n = 0; n < 4; ++n) acc[mm][n] = (f32x4){0.f, 0.f, 0.f, 0.f};

  auto stageA = [&](int c, int buf) {
    int row = 8 * w + (l >> 3);
    int ss = (l & 7) ^ (row & 7);
    gload16(xbf + ((size_t)(r0 + row) * Dn + c * 64 + ss * 8),
            (char*)&as_[buf][0] + w * 1024);
  };
  auto stageB = [&](int c, int buf) {
#pragma unroll
    for (int ii = 0; ii < 4; ++ii) {
      int i = 4 * w + ii;
      int n = i * 8 + (l >> 3);
      int ss = (l & 7) ^ (n & 7);
      gload16(WqkT + ((size_t)n * Dn + c * 64 + ss * 8),
              (char*)&bs_[buf][0] + i * 1024);
    }
  };
  stageA(0, 0); stageB(0, 0);
  __syncthreads();
  for (int c = 0; c < 8; ++c) {
    if (c + 1 < 8) { stageA(c + 1, (c + 1) & 1); stageB(c + 1, (c + 1) & 1); }
    const u16* ab = &as_[c & 1][0];
    const u16* bb = &bs_[c & 1][0];
#pragma unroll
    for (int kk = 0; kk < 2; ++kk) {
      int rA0 = wr * 32 + (l & 15);
      int sA = ((l >> 4) + 4 * kk) ^ (rA0 & 7);
      bf16x8 a0 = *(const bf16x8*)(ab + rA0 * 64 + sA * 8);
      bf16x8 a1 = *(const bf16x8*)(ab + (rA0 + 16) * 64 + sA * 8);
#pragma unroll
      for (int n = 0; n < 4; ++n) {
        int rB = wc * 64 + n * 16 + (l & 15);
        int sB = ((l >> 4) + 4 * kk) ^ (rB & 7);
        bf16x8 bv = *(const bf16x8*)(bb + rB * 64 + sB * 8);
        acc[0][n] = mfma16(a0, bv, acc[0][n]);
        acc[1][n] = mfma16(a1, bv, acc[1][n]);
      }
    }
    __syncthreads();
  }
#pragma unroll
  for (int n = 0; n < 4; ++n) {
    int col = wc * 64 + n * 16 + (l & 15);
    float bias = (col < 128) ? bq[col] : bk[col - 128];
    u16* outp = (col < 128) ? (qbf + col) : (kbf + col - 128);
#pragma unroll
    for (int mm = 0; mm < 2; ++mm)
#pragma unroll
      for (int i = 0; i < 4; ++i) {
        int row = r0 + wr * 32 + mm * 16 + 4 * (l >> 4) + i;
        outp[(size_t)row * DKn] = f2bf(acc[mm][n][i] + bias);
      }
  }
}

// ---------------------------------------------------------------------------
// Kernel 4: banded scores via MFMA + 3-window softmax -> combined weights.
// ---------------------------------------------------------------------------
__global__ __launch_bounds__(512) void weights_kernel(
    const u16* __restrict__ qbf, const u16* __restrict__ kbf,
    u16* __restrict__ Wg) {
  __shared__ u16 qs[QB * DKn];        // 16 KB
  __shared__ u16 ks[2][QB * DKn];     // 2 x 16 KB
  __shared__ u16 S[QB * SST];         // ~104 KB
  const int tid = threadIdx.x;
  const int w = tid >> 6, l = tid & 63;
  const int blk = blockIdx.x;
  const int b = blk >> 5;
  const int t064 = (blk & 31) * QB;
  const int jbase = t064 - 360;

#pragma unroll
  for (int ii = 0; ii < 2; ++ii) {
    int i = 2 * w + ii;
    int row = i * 4 + (l >> 4);
    int ss = (l & 15) ^ (row & 15);
    gload16(qbf + ((size_t)(b * Tn + t064 + row) * DKn + ss * 8),
            (char*)qs + i * 1024);
  }
#pragma unroll
  for (int ii = 0; ii < 2; ++ii) {
    int i = 2 * w + ii;
    int row = i * 4 + (l >> 4);
    int j = jbase + row; j = j < 0 ? 0 : (j > Tn - 1 ? Tn - 1 : j);
    int ss = (l & 15) ^ (row & 15);
    gload16(kbf + ((size_t)(b * Tn + j) * DKn + ss * 8),
            (char*)&ks[0][0] + i * 1024);
  }
  __syncthreads();

  const int mw = w >> 1, nh = w & 1;
  const int rA = mw * 16 + (l & 15);
  const float scale = 0.08838834764831845f;   // 1/sqrt(128)

  for (int c = 0; c < NCH; ++c) {
    if (c + 1 < NCH) {
#pragma unroll
      for (int ii = 0; ii < 2; ++ii) {
        int i = 2 * w + ii;
        int row = i * 4 + (l >> 4);
        int j = jbase + (c + 1) * 64 + row;
        j = j < 0 ? 0 : (j > Tn - 1 ? Tn - 1 : j);
        int ss = (l & 15) ^ (row & 15);
        gload16(kbf + ((size_t)(b * Tn + j) * DKn + ss * 8),
                (char*)&ks[(c + 1) & 1][0] + i * 1024);
      }
    }
    const u16* kb = &ks[c & 1][0];
    f32x4 acc0 = {0.f,0.f,0.f,0.f}, acc1 = {0.f,0.f,0.f,0.f};
#pragma unroll
    for (int kk = 0; kk < 4; ++kk) {
      int sa = ((l >> 4) + 4 * kk) ^ (rA & 15);
      bf16x8 a = *(const bf16x8*)(qs + rA * DKn + sa * 8);
      int rB0 = nh * 32 + (l & 15);
      int sb0 = ((l >> 4) + 4 * kk) ^ (rB0 & 15);
      bf16x8 b0 = *(const bf16x8*)(kb + rB0 * DKn + sb0 * 8);
      int rB1 = rB0 + 16;
      int sb1 = ((l >> 4) + 4 * kk) ^ (rB1 & 15);
      bf16x8 b1 = *(const bf16x8*)(kb + rB1 * DKn + sb1 * 8);
      acc0 = mfma16(a, b0, acc0);
      acc1 = mfma16(a, b1, acc1);
    }
    int srow = mw * 16 + 4 * (l >> 4);
    int col0 = c * 64 + nh * 32 + (l & 15);
#pragma unroll
    for (int i = 0; i < 4; ++i) {
      S[(srow + i) * SST + col0]      = f2bf(acc0[i] * scale);
      S[(srow + i) * SST + col0 + 16] = f2bf(acc1[i] * scale);
    }
    __syncthreads();
  }

  const int jjminv = jbase < 0 ? -jbase : 0;
  int jjmaxv = (Tn - 1) - jbase; if (jjmaxv > WJ - 1) jjmaxv = WJ - 1;
  u16* wout = Wg + (size_t)blk * QB * WJ;
  for (int r = w * 8; r < w * 8 + 8; ++r) {
    const int center = r + 360;
    float m[3], il[3];
    const int hw[3] = {12, 84, 360};
#pragma unroll
    for (int wi = 0; wi < 3; ++wi) {
      int lo = center - hw[wi]; if (lo < jjminv) lo = jjminv;
      int hi = center + hw[wi]; if (hi > jjmaxv) hi = jjmaxv;
      float mm = -1e30f;
      for (int jj = lo + l; jj <= hi; jj += 64)
        mm = fmaxf(mm, bf2f(S[r * SST + jj]));
#pragma unroll
      for (int o = 32; o; o >>= 1) mm = fmaxf(mm, __shfl_xor(mm, o));
      float sum = 0.f;
      for (int jj = lo + l; jj <= hi; jj += 64)
        sum += __expf(bf2f(S[r * SST + jj]) - mm);
#pragma unroll
      for (int o = 32; o; o >>= 1) sum += __shfl_xor(sum, o);
      m[wi] = mm; il[wi] = 1.f / sum;
    }
    for (int jj = l; jj < WJ; jj += 64) {
      float cc = 0.f;
      if (jj >= jjminv && jj <= jjmaxv) {
        float s = bf2f(S[r * SST + jj]);
        int d = jj - center; d = d < 0 ? -d : d;
        if (d <= 12)  cc += __expf(s - m[0]) * il[0];
        if (d <= 84)  cc += __expf(s - m[1]) * il[1];
        if (d <= 360) cc += __expf(s - m[2]) * il[2];
      }
      wout[r * WJ + jj] = f2bf(cc * (1.f / 3.f));
    }
  }
}

// ---------------------------------------------------------------------------
// Kernel 5: PV GEMM.  OUT[64 x 512] = Wg[64 x 832] @ xwin[832 x 512].
// ---------------------------------------------------------------------------
__global__ __launch_bounds__(512) void pv_kernel(
    const u16* __restrict__ Wg, const u16* __restrict__ xT,
    u16* __restrict__ accbf) {
  __shared__ u16 xs[2][Dn * 64];   // 2 x 64 KB
  __shared__ u16 ws[2][QB * 64];   // 2 x 8 KB
  const int tid = threadIdx.x;
  const int w = tid >> 6, l = tid & 63;
  const int blk = blockIdx.x;
  const int b = blk >> 5;
  const int t064 = (blk & 31) * QB;
  const int jbase = t064 - 360;
  const int wr = w >> 2, wc = w & 3;

  f32x4 acc[2][8];
#pragma unroll
  for (int mm = 0; mm < 2; ++mm)
#pragma unroll
    for (int n = 0; n < 8; ++n) acc[mm][n] = (f32x4){0.f,0.f,0.f,0.f};

  auto stage = [&](int c, int buf) {
    for (int ii = 0; ii < 8; ++ii) {
      int i = 8 * w + ii;
      int d = i * 8 + (l >> 3);
      int ss = (l & 7) ^ (d & 7);
      int g = jbase + c * 64 + ss * 8;
      g = g < 0 ? 0 : (g > Tn - 8 ? Tn - 8 : g);
      gload16(xT + ((size_t)(b * Dn + d) * Tn + g),
              (char*)&xs[buf][0] + i * 1024);
    }
    int row = 8 * w + (l >> 3);
    int ss = (l & 7) ^ (row & 7);
    gload16(Wg + ((size_t)(blk * QB + row)) * WJ + c * 64 + ss * 8,
            (char*)&ws[buf][0] + w * 1024);
  };

  stage(0, 0);
  __syncthreads();
  for (int c = 0; c < NCH; ++c) {
    if (c + 1 < NCH) stage(c + 1, (c + 1) & 1);
    const u16* xb = &xs[c & 1][0];
    const u16* wb = &ws[c & 1][0];
#pragma unroll
    for (int kk = 0; kk < 2; ++kk) {
      int rA0 = wr * 32 + (l & 15);
      int sA = ((l >> 4) + 4 * kk) ^ (rA0 & 7);
      bf16x8 a0 = *(const bf16x8*)(wb + rA0 * 64 + sA * 8);
      bf16x8 a1 = *(const bf16x8*)(wb + (rA0 + 16) * 64 + sA * 8);
#pragma unroll
      for (int n = 0; n < 8; ++n) {
        int rB = wc * 128 + n * 16 + (l & 15);
        int sB = ((l >> 4) + 4 * kk) ^ (rB & 7);
        bf16x8 bv = *(const bf16x8*)(xb + rB * 64 + sB * 8);
        acc[0][n] = mfma16(a0, bv, acc[0][n]);
        acc[1][n] = mfma16(a1, bv, acc[1][n]);
      }
    }
    __syncthreads();
  }
#pragma unroll
  for (int mm = 0; mm < 2; ++mm)
#pragma unroll
    for (int n = 0; n < 8; ++n)
#pragma unroll
      for (int i = 0; i < 4; ++i) {
        int row = wr * 32 + mm * 16 + 4 * (l >> 4) + i;
        int col = wc * 128 + n * 16 + (l & 15);
        accbf[(size_t)(b * Tn + t064 + row) * Dn + col] = f2bf(acc[mm][n][i]);
      }
}

// ---------------------------------------------------------------------------
// Kernel 6: OUT = LN(accbf @ WoT^T + bo + x) * gamma + beta, MFMA fused.
// Block = 64 rows x 512 cols, K = 512.
// ---------------------------------------------------------------------------
__global__ __launch_bounds__(512) void out_ln_mfma_kernel(
    const u16* __restrict__ accbf, const float* __restrict__ x,
    const u16* __restrict__ WoT, const float* __restrict__ bo,
    const float* __restrict__ gamma, const float* __restrict__ beta,
    float* __restrict__ out) {
  __shared__ u16 as_[2][64 * 64];     // 2 x 8 KB
  __shared__ u16 bs_[2][512 * 64];    // 2 x 64 KB
  __shared__ float red[64][4][2];     // 2 KB
  const int tid = threadIdx.x, w = tid >> 6, l = tid & 63;
  const int r0 = blockIdx.x * 64;
  const int wr = w >> 2, wc = w & 3;

  f32x4 acc[2][8];
#pragma unroll
  for (int mm = 0; mm < 2; ++mm)
#pragma unroll
    for (int n = 0; n < 8; ++n) acc[mm][n] = (f32x4){0.f,0.f,0.f,0.f};

  auto stageA = [&](int c, int buf) {
    int row = 8 * w + (l >> 3);
    int ss = (l & 7) ^ (row & 7);
    gload16(accbf + ((size_t)(r0 + row) * Dn + c * 64 + ss * 8),
            (char*)&as_[buf][0] + w * 1024);
  };
  auto stageB = [&](int c, int buf) {
#pragma unroll
    for (int ii = 0; ii < 8; ++ii) {
      int i = 8 * w + ii;
      int n = i * 8 + (l >> 3);
      int ss = (l & 7) ^ (n & 7);
      gload16(WoT + ((size_t)n * Dn + c * 64 + ss * 8),
              (char*)&bs_[buf][0] + i * 1024);
    }
  };
  stageA(0, 0); stageB(0, 0);
  __syncthreads();
  for (int c = 0; c < 8; ++c) {
    if (c + 1 < 8) { stageA(c + 1, (c + 1) & 1); stageB(c + 1, (c + 1) & 1); }
    const u16* ab = &as_[c & 1][0];
    const u16* bb = &bs_[c & 1][0];
#pragma unroll
    for (int kk = 0; kk < 2; ++kk) {
      int rA0 = wr * 32 + (l & 15);
      int sA = ((l >> 4) + 4 * kk) ^ (rA0 & 7);
      bf16x8 a0 = *(const bf16x8*)(ab + rA0 * 64 + sA * 8);
      bf16x8 a1 = *(const bf16x8*)(ab + (rA0 + 16) * 64 + sA * 8);
#pragma unroll
      for (int n = 0; n < 8; ++n) {
        int rB = wc * 128 + n * 16 + (l & 15);
        int sB = ((l >> 4) + 4 * kk) ^ (rB & 7);
        bf16x8 bv = *(const bf16x8*)(bb + rB * 64 + sB * 8);
        acc[0][n] = mfma16(a0, bv, acc[0][n]);
        acc[1][n] = mfma16(a1, bv, acc[1][n]);
      }
    }
    __syncthreads();
  }

  // epilogue: bias + residual, then LayerNorm
  float g_[8], be_[8], bo_[8];
#pragma unroll
  for (int n = 0; n < 8; ++n) {
    int col = wc * 128 + n * 16 + (l & 15);
    bo_[n] = bo[col]; g_[n] = gamma[col]; be_[n] = beta[col];
  }
#pragma unroll
  for (int mm = 0; mm < 2; ++mm)
#pragma unroll
    for (int i = 0; i < 4; ++i) {
      int row = r0 + wr * 32 + mm * 16 + 4 * (l >> 4) + i;
#pragma unroll
      for (int n = 0; n < 8; ++n) {
        int col = wc * 128 + n * 16 + (l & 15);
        acc[mm][n][i] += bo_[n] + x[(size_t)row * Dn + col];
      }
    }
#pragma unroll
  for (int mm = 0; mm < 2; ++mm)
#pragma unroll
    for (int i = 0; i < 4; ++i) {
      float s = 0.f, s2 = 0.f;
#pragma unroll
      for (int n = 0; n < 8; ++n) { float v = acc[mm][n][i]; s += v; s2 += v * v; }
#pragma unroll
      for (int o = 8; o; o >>= 1) { s += __shfl_xor(s, o); s2 += __shfl_xor(s2, o); }
      if ((l & 15) == 0) {
        int rl = wr * 32 + mm * 16 + 4 * (l >> 4) + i;
        red[rl][wc][0] = s; red[rl][wc][1] = s2;
      }
    }
  __syncthreads();
#pragma unroll
  for (int mm = 0; mm < 2; ++mm)
#pragma unroll
    for (int i = 0; i < 4; ++i) {
      int rl = wr * 32 + mm * 16 + 4 * (l >> 4) + i;
      float s  = red[rl][0][0] + red[rl][1][0] + red[rl][2][0] + red[rl][3][0];
      float s2 = red[rl][0][1] + red[rl][1][1] + red[rl][2][1] + red[rl][3][1];
      float mean = s * (1.f / 512.f);
      float var  = s2 * (1.f / 512.f) - mean * mean;
      float inv  = rsqrtf(var + 1e-5f);
      int row = r0 + rl;
#pragma unroll
      for (int n = 0; n < 8; ++n) {
        int col = wc * 128 + n * 16 + (l & 15);
        out[(size_t)row * Dn + col] = (acc[mm][n][i] - mean) * inv * g_[n] + be_[n];
      }
    }
}

// ---------------------------------------------------------------------------
extern "C" void kernel_launch(void* const* d_in, const int* in_sizes, int n_in,
                              void* d_out, int out_size, void* d_ws, size_t ws_size,
                              hipStream_t stream) {
  const float* x     = (const float*)d_in[0];
  const float* Wq    = (const float*)d_in[1];
  const float* bq    = (const float*)d_in[2];
  const float* Wk    = (const float*)d_in[3];
  const float* bk    = (const float*)d_in[4];
  const float* Wo    = (const float*)d_in[5];
  const float* bo    = (const float*)d_in[6];
  const float* gamma = (const float*)d_in[7];
  const float* beta  = (const float*)d_in[8];
  float* out = (float*)d_out;

  // workspace (u16 elems)
  u16* qbf   = (u16*)d_ws;
  u16* kbf   = qbf   + (size_t)Bn * Tn * DKn;          // +2,097,152
  u16* xT    = kbf   + (size_t)Bn * Tn * DKn;          // +2,097,152
  u16* xbf   = xT    + (size_t)Bn * Dn * Tn;           // +8,388,608
  u16* Wg    = xbf   + (size_t)Bn * Tn * Dn;           // +8,388,608
  u16* accbf = Wg    + (size_t)Bn * 32 * QB * WJ;      // +13,631,488
  u16* WqkT  = accbf + (size_t)Bn * Tn * Dn;           // +8,388,608
  u16* WoT   = WqkT  + (size_t)256 * 512;              // +131,072

  xpose_kernel<<<Bn * 256, 256, 0, stream>>>(x, xT, xbf);
  wprep_kernel<<<96, 256, 0, stream>>>(Wq, Wk, Wo, WqkT, WoT);
  qk_mfma_kernel<<<Bn * Tn / 64, 512, 0, stream>>>(xbf, WqkT, bq, bk, qbf, kbf);
  weights_kernel<<<Bn * 32, 512, 0, stream>>>(qbf, kbf, Wg);
  pv_kernel<<<Bn * 32, 512, 0, stream>>>(Wg, xT, accbf);
  out_ln_mfma_kernel<<<Bn * Tn / 64, 512, 0, stream>>>(accbf, x, WoT, bo, gamma, beta, out);
}

// Round 4
// 147.180 us; speedup vs baseline: 7.7818x; 1.0847x over previous
//
#include <hip/hip_runtime.h>

typedef unsigned short u16;
typedef __attribute__((ext_vector_type(4))) unsigned short u16x4;
typedef __attribute__((ext_vector_type(8))) unsigned short u16x8;
typedef __attribute__((ext_vector_type(8))) short bf16x8;
typedef __attribute__((ext_vector_type(4))) float f32x4;

constexpr int Bn = 8, Tn = 2048, Dn = 512, DKn = 128;
constexpr int QB = 64;      // query rows per pv block
constexpr int WJ = 832;     // padded union window for pv = 13*64
constexpr int NCH = 13;     // pv K-chunks of 64
constexpr int WQB = 32;     // query rows per weights block
constexpr int WST = 776;    // weights S LDS stride (u16): 768 + 8 pad

__device__ inline u16 f2bf(float f) {
  unsigned u = __float_as_uint(f);
  return (u16)((u + 0x7FFFu + ((u >> 16) & 1u)) >> 16);
}
__device__ inline float bf2f(u16 h) {
  return __uint_as_float(((unsigned)h) << 16);
}
__device__ inline void gload16(const void* g, void* l) {
  __builtin_amdgcn_global_load_lds(
      (const __attribute__((address_space(1))) unsigned int*)g,
      (__attribute__((address_space(3))) unsigned int*)l, 16, 0, 0);
}
__device__ inline f32x4 mfma16(bf16x8 a, bf16x8 b, f32x4 c) {
  return __builtin_amdgcn_mfma_f32_16x16x32_bf16(a, b, c, 0, 0, 0);
}

// ---------------------------------------------------------------------------
// Kernel 1: xT[b][d][t] = bf16(x[b][t][d]) AND xbf[b][t][d] = bf16(x[b][t][d]).
// ---------------------------------------------------------------------------
__global__ __launch_bounds__(256) void xpose_kernel(
    const float* __restrict__ x, u16* __restrict__ xT, u16* __restrict__ xbf) {
  __shared__ u16 tile[64][72];
  const int blk = blockIdx.x;
  const int b = blk >> 8;                 // 256 tiles per batch
  const int rem = blk & 255;
  const int t0 = (rem >> 3) * 64, d0 = (rem & 7) * 64;
  const int tid = threadIdx.x;

#pragma unroll
  for (int it = 0; it < 4; ++it) {
    int r = (tid >> 4) + it * 16;
    int c = (tid & 15) * 4;
    float4 v = *(const float4*)&x[(size_t)(b * Tn + t0 + r) * Dn + d0 + c];
    u16 b0 = f2bf(v.x), b1 = f2bf(v.y), b2 = f2bf(v.z), b3 = f2bf(v.w);
    tile[c + 0][r] = b0;
    tile[c + 1][r] = b1;
    tile[c + 2][r] = b2;
    tile[c + 3][r] = b3;
    u16x4 pv; pv[0] = b0; pv[1] = b1; pv[2] = b2; pv[3] = b3;
    *(u16x4*)&xbf[(size_t)(b * Tn + t0 + r) * Dn + d0 + c] = pv;
  }
  __syncthreads();
  const int dr = tid >> 2, ts = (tid & 3) * 16;
  u16x8 v0 = *(const u16x8*)&tile[dr][ts];
  u16x8 v1 = *(const u16x8*)&tile[dr][ts + 8];
  u16* dst = xT + (size_t)(b * Dn + d0 + dr) * Tn + t0 + ts;
  *(u16x8*)dst = v0;
  *(u16x8*)(dst + 8) = v1;
}

// ---------------------------------------------------------------------------
// Kernel 2: weight prep.  WqkT[n][d] = bf16(Wq|Wk[d][n]) (n<128 -> Wq),
//           WoT[n][d] = bf16(Wo[d][n]).
// ---------------------------------------------------------------------------
__global__ __launch_bounds__(256) void wprep_kernel(
    const float* __restrict__ Wq, const float* __restrict__ Wk,
    const float* __restrict__ Wo,
    u16* __restrict__ WqkT, u16* __restrict__ WoT) {
  __shared__ u16 tile[64][72];
  const int tid = threadIdx.x;
  const int blk = blockIdx.x;
  const float* src; u16* dst;
  int srcC, r0, c0, rowOff;
  if (blk < 32) {
    src = (blk < 16) ? Wq : Wk;
    rowOff = (blk < 16) ? 0 : 128;
    int t = blk & 15;
    r0 = (t >> 1) * 64; c0 = (t & 1) * 64;
    srcC = 128; dst = WqkT;
  } else {
    int t = blk - 32;
    src = Wo; rowOff = 0;
    r0 = (t >> 3) * 64; c0 = (t & 7) * 64;
    srcC = 512; dst = WoT;
  }
#pragma unroll
  for (int it = 0; it < 4; ++it) {
    int r = (tid >> 4) + it * 16;
    int c = (tid & 15) * 4;
    float4 v = *(const float4*)&src[(size_t)(r0 + r) * srcC + c0 + c];
    tile[c + 0][r] = f2bf(v.x);
    tile[c + 1][r] = f2bf(v.y);
    tile[c + 2][r] = f2bf(v.z);
    tile[c + 3][r] = f2bf(v.w);
  }
  __syncthreads();
  const int dr = tid >> 2, ts = (tid & 3) * 16;
  u16x8 v0 = *(const u16x8*)&tile[dr][ts];
  u16x8 v1 = *(const u16x8*)&tile[dr][ts + 8];
  u16* dp = dst + (size_t)(rowOff + c0 + dr) * 512 + r0 + ts;
  *(u16x8*)dp = v0;
  *(u16x8*)(dp + 8) = v1;
}

// ---------------------------------------------------------------------------
// Kernel 3: q|k = xbf @ WqkT^T + bias, MFMA.  Block = 64 rows x 256 cols.
// ---------------------------------------------------------------------------
__global__ __launch_bounds__(512) void qk_mfma_kernel(
    const u16* __restrict__ xbf, const u16* __restrict__ WqkT,
    const float* __restrict__ bq, const float* __restrict__ bk,
    u16* __restrict__ qbf, u16* __restrict__ kbf) {
  __shared__ u16 as_[2][64 * 64];     // 2 x 8 KB
  __shared__ u16 bs_[2][256 * 64];    // 2 x 32 KB
  const int tid = threadIdx.x, w = tid >> 6, l = tid & 63;
  const int r0 = blockIdx.x * 64;
  const int wr = w >> 2, wc = w & 3;  // wave tile: 32 rows x 64 cols

  f32x4 acc[2][4];
#pragma unroll
  for (int mm = 0; mm < 2; ++mm)
#pragma unroll
    for (int n = 0; n < 4; ++n) acc[mm][n] = (f32x4){0.f, 0.f, 0.f, 0.f};

  auto stageA = [&](int c, int buf) {
    int row = 8 * w + (l >> 3);
    int ss = (l & 7) ^ (row & 7);
    gload16(xbf + ((size_t)(r0 + row) * Dn + c * 64 + ss * 8),
            (char*)&as_[buf][0] + w * 1024);
  };
  auto stageB = [&](int c, int buf) {
#pragma unroll
    for (int ii = 0; ii < 4; ++ii) {
      int i = 4 * w + ii;
      int n = i * 8 + (l >> 3);
      int ss = (l & 7) ^ (n & 7);
      gload16(WqkT + ((size_t)n * Dn + c * 64 + ss * 8),
              (char*)&bs_[buf][0] + i * 1024);
    }
  };
  stageA(0, 0); stageB(0, 0);
  __syncthreads();
  for (int c = 0; c < 8; ++c) {
    if (c + 1 < 8) { stageA(c + 1, (c + 1) & 1); stageB(c + 1, (c + 1) & 1); }
    const u16* ab = &as_[c & 1][0];
    const u16* bb = &bs_[c & 1][0];
#pragma unroll
    for (int kk = 0; kk < 2; ++kk) {
      int rA0 = wr * 32 + (l & 15);
      int sA = ((l >> 4) + 4 * kk) ^ (rA0 & 7);
      bf16x8 a0 = *(const bf16x8*)(ab + rA0 * 64 + sA * 8);
      bf16x8 a1 = *(const bf16x8*)(ab + (rA0 + 16) * 64 + sA * 8);
#pragma unroll
      for (int n = 0; n < 4; ++n) {
        int rB = wc * 64 + n * 16 + (l & 15);
        int sB = ((l >> 4) + 4 * kk) ^ (rB & 7);
        bf16x8 bv = *(const bf16x8*)(bb + rB * 64 + sB * 8);
        acc[0][n] = mfma16(a0, bv, acc[0][n]);
        acc[1][n] = mfma16(a1, bv, acc[1][n]);
      }
    }
    __syncthreads();
  }
#pragma unroll
  for (int n = 0; n < 4; ++n) {
    int col = wc * 64 + n * 16 + (l & 15);
    float bias = (col < 128) ? bq[col] : bk[col - 128];
    u16* outp = (col < 128) ? (qbf + col) : (kbf + col - 128);
#pragma unroll
    for (int mm = 0; mm < 2; ++mm)
#pragma unroll
      for (int i = 0; i < 4; ++i) {
        int row = r0 + wr * 32 + mm * 16 + 4 * (l >> 4) + i;
        outp[(size_t)row * DKn] = f2bf(acc[mm][n][i] + bias);
      }
  }
}

// ---------------------------------------------------------------------------
// Kernel 4: banded scores + 3-window softmax -> combined weights.
// Block = 32 query rows, 512 threads.  No k/q LDS; barrier-free MFMA loop.
// Ring decomposition: ring0 d<=12, ring1 13..84, ring2 85..360.
// Writes into the 64-row pv tile layout: Wg[pvblk][64][832].
// ---------------------------------------------------------------------------
__global__ __launch_bounds__(512) void weights_kernel(
    const u16* __restrict__ qbf, const u16* __restrict__ kbf,
    u16* __restrict__ Wg) {
  __shared__ u16 S[WQB * WST];          // 48.5 KB bf16 scores
  __shared__ float mpart[4][WQB][3];    // 1.5 KB ring-max partials
  const int tid = threadIdx.x, w = tid >> 6, l = tid & 63;
  const int blk = blockIdx.x;           // 512 blocks
  const int b = blk >> 6;
  const int tt = blk & 63;
  const int t0 = tt * WQB;
  const int jbase = t0 - 360;
  const int mw = w >> 2, nh = w & 3;
  const float scale = 0.08838834764831845f;   // 1/sqrt(128)

  // q fragments in registers (16 rows per mw group)
  bf16x8 a[4];
  {
    int row = t0 + mw * 16 + (l & 15);
    const u16* qp = qbf + (size_t)(b * Tn + row) * DKn + (l >> 4) * 8;
#pragma unroll
    for (int kk = 0; kk < 4; ++kk) a[kk] = *(const bf16x8*)(qp + kk * 32);
  }

  float m0[4], m1[4], m2[4];
#pragma unroll
  for (int i = 0; i < 4; ++i) { m0[i] = -1e30f; m1[i] = -1e30f; m2[i] = -1e30f; }
  const int rbase = mw * 16 + 4 * (l >> 4);

  // MFMA loop: 12 chunks of 64 k, B-fragments direct from global, no barriers
  for (int c = 0; c < 12; ++c) {
    int jj = c * 64 + nh * 16 + (l & 15);
    int j = jbase + jj;
    int jc = j < 0 ? 0 : (j > Tn - 1 ? Tn - 1 : j);
    const u16* kp = kbf + (size_t)(b * Tn + jc) * DKn + (l >> 4) * 8;
    f32x4 acc = {0.f, 0.f, 0.f, 0.f};
#pragma unroll
    for (int kk = 0; kk < 4; ++kk)
      acc = mfma16(a[kk], *(const bf16x8*)(kp + kk * 32), acc);
    bool valid = (j >= 0) && (j < Tn);
#pragma unroll
    for (int i = 0; i < 4; ++i) {
      float v = acc[i] * scale;
      int r = rbase + i;
      S[r * WST + jj] = f2bf(v);
      int dist = jj - r - 360; dist = dist < 0 ? -dist : dist;
      m0[i] = (valid && dist <= 12) ? fmaxf(m0[i], v) : m0[i];
      m1[i] = (valid && dist > 12 && dist <= 84) ? fmaxf(m1[i], v) : m1[i];
      m2[i] = (valid && dist > 84 && dist <= 360) ? fmaxf(m2[i], v) : m2[i];
    }
  }

  // reduce ring maxes over the 16 k-lanes (l&15), store per-nh partials
#pragma unroll
  for (int o = 1; o < 16; o <<= 1)
#pragma unroll
    for (int i = 0; i < 4; ++i) {
      m0[i] = fmaxf(m0[i], __shfl_xor(m0[i], o));
      m1[i] = fmaxf(m1[i], __shfl_xor(m1[i], o));
      m2[i] = fmaxf(m2[i], __shfl_xor(m2[i], o));
    }
  if ((l & 15) == 0) {
#pragma unroll
    for (int i = 0; i < 4; ++i) {
      mpart[nh][rbase + i][0] = m0[i];
      mpart[nh][rbase + i][1] = m1[i];
      mpart[nh][rbase + i][2] = m2[i];
    }
  }
  __syncthreads();

  // passes B (ring sums) + C (combine & write).  Wave w owns rows 4w..4w+3.
  const int off32 = (tt & 1) * 32;
  const int pvblk = b * 32 + (tt >> 1);
  u16* wout = Wg + ((size_t)pvblk * QB + off32) * WJ;
#pragma unroll
  for (int rr = 0; rr < 4; ++rr) {
    int r = 4 * w + rr;
    float mr0 = fmaxf(fmaxf(mpart[0][r][0], mpart[1][r][0]),
                      fmaxf(mpart[2][r][0], mpart[3][r][0]));
    float mr1 = fmaxf(fmaxf(mpart[0][r][1], mpart[1][r][1]),
                      fmaxf(mpart[2][r][1], mpart[3][r][1]));
    float mr2 = fmaxf(fmaxf(mpart[0][r][2], mpart[1][r][2]),
                      fmaxf(mpart[2][r][2], mpart[3][r][2]));
    float M2 = fmaxf(mr0, mr1);
    float M  = fmaxf(M2, mr2);
    const int center = r + 360;

    float s0 = 0.f, s1 = 0.f, s2 = 0.f;
#pragma unroll
    for (int t = 0; t < 6; ++t) {
      int jj = 2 * l + 128 * t;
      unsigned pv2 = *(const unsigned*)&S[r * WST + jj];
#pragma unroll
      for (int h = 0; h < 2; ++h) {
        int jjh = jj + h;
        float s = bf2f((u16)(h ? (pv2 >> 16) : (pv2 & 0xffff)));
        int j = jbase + jjh;
        bool valid = (j >= 0) && (j < Tn);
        int dist = jjh - center; dist = dist < 0 ? -dist : dist;
        float mref = dist <= 12 ? mr0 : (dist <= 84 ? mr1 : mr2);
        float e = __expf(s - mref);
        e = (valid && dist <= 360) ? e : 0.f;
        s0 += (dist <= 12) ? e : 0.f;
        s1 += (dist > 12 && dist <= 84) ? e : 0.f;
        s2 += (dist > 84) ? e : 0.f;
      }
    }
#pragma unroll
    for (int o = 32; o; o >>= 1) {
      s0 += __shfl_xor(s0, o);
      s1 += __shfl_xor(s1, o);
      s2 += __shfl_xor(s2, o);
    }
    float l1 = s0;
    float l2 = s0 * __expf(mr0 - M2) + s1 * __expf(mr1 - M2);
    float l3 = s0 * __expf(mr0 - M) + s1 * __expf(mr1 - M) + s2 * __expf(mr2 - M);
    float F2w = (1.f / 3.f) / l3;
    float F1w = (1.f / 3.f) * __expf(M - M2) / l2 + F2w;
    float F0w = (1.f / 3.f) * __expf(M - mr0) / l1 + F1w;

    // pass C: write all 832 pv-layout columns for row rp = off32 + r
#pragma unroll
    for (int t = 0; t < 13; ++t) {
      int jjp = l + 64 * t;
      int jjw = jjp - off32;
      float cc = 0.f;
      if (jjw >= 0 && jjw < 768) {
        int j = jbase + jjw;
        bool valid = (j >= 0) && (j < Tn);
        int dist = jjw - center; dist = dist < 0 ? -dist : dist;
        float s = bf2f(S[r * WST + jjw]);
        float F = dist <= 12 ? F0w : (dist <= 84 ? F1w : F2w);
        float e = __expf(s - M) * F;
        cc = (valid && dist <= 360) ? e : 0.f;
      }
      wout[(size_t)r * WJ + jjp] = f2bf(cc);
    }
  }
}

// ---------------------------------------------------------------------------
// Kernel 5: PV GEMM.  OUT[64 x 512] = Wg[64 x 832] @ xwin[832 x 512].
// ---------------------------------------------------------------------------
__global__ __launch_bounds__(512) void pv_kernel(
    const u16* __restrict__ Wg, const u16* __restrict__ xT,
    u16* __restrict__ accbf) {
  __shared__ u16 xs[2][Dn * 64];   // 2 x 64 KB
  __shared__ u16 ws[2][QB * 64];   // 2 x 8 KB
  const int tid = threadIdx.x;
  const int w = tid >> 6, l = tid & 63;
  const int blk = blockIdx.x;
  const int b = blk >> 5;
  const int t064 = (blk & 31) * QB;
  const int jbase = t064 - 360;
  const int wr = w >> 2, wc = w & 3;

  f32x4 acc[2][8];
#pragma unroll
  for (int mm = 0; mm < 2; ++mm)
#pragma unroll
    for (int n = 0; n < 8; ++n) acc[mm][n] = (f32x4){0.f,0.f,0.f,0.f};

  auto stage = [&](int c, int buf) {
    for (int ii = 0; ii < 8; ++ii) {
      int i = 8 * w + ii;
      int d = i * 8 + (l >> 3);
      int ss = (l & 7) ^ (d & 7);
      int g = jbase + c * 64 + ss * 8;
      g = g < 0 ? 0 : (g > Tn - 8 ? Tn - 8 : g);
      gload16(xT + ((size_t)(b * Dn + d) * Tn + g),
              (char*)&xs[buf][0] + i * 1024);
    }
    int row = 8 * w + (l >> 3);
    int ss = (l & 7) ^ (row & 7);
    gload16(Wg + ((size_t)(blk * QB + row)) * WJ + c * 64 + ss * 8,
            (char*)&ws[buf][0] + w * 1024);
  };

  stage(0, 0);
  __syncthreads();
  for (int c = 0; c < NCH; ++c) {
    if (c + 1 < NCH) stage(c + 1, (c + 1) & 1);
    const u16* xb = &xs[c & 1][0];
    const u16* wb = &ws[c & 1][0];
#pragma unroll
    for (int kk = 0; kk < 2; ++kk) {
      int rA0 = wr * 32 + (l & 15);
      int sA = ((l >> 4) + 4 * kk) ^ (rA0 & 7);
      bf16x8 a0 = *(const bf16x8*)(wb + rA0 * 64 + sA * 8);
      bf16x8 a1 = *(const bf16x8*)(wb + (rA0 + 16) * 64 + sA * 8);
#pragma unroll
      for (int n = 0; n < 8; ++n) {
        int rB = wc * 128 + n * 16 + (l & 15);
        int sB = ((l >> 4) + 4 * kk) ^ (rB & 7);
        bf16x8 bv = *(const bf16x8*)(xb + rB * 64 + sB * 8);
        acc[0][n] = mfma16(a0, bv, acc[0][n]);
        acc[1][n] = mfma16(a1, bv, acc[1][n]);
      }
    }
    __syncthreads();
  }
#pragma unroll
  for (int mm = 0; mm < 2; ++mm)
#pragma unroll
    for (int n = 0; n < 8; ++n)
#pragma unroll
      for (int i = 0; i < 4; ++i) {
        int row = wr * 32 + mm * 16 + 4 * (l >> 4) + i;
        int col = wc * 128 + n * 16 + (l & 15);
        accbf[(size_t)(b * Tn + t064 + row) * Dn + col] = f2bf(acc[mm][n][i]);
      }
}

// ---------------------------------------------------------------------------
// Kernel 6: OUT = LN(accbf @ WoT^T + bo + x) * gamma + beta, MFMA fused.
// ---------------------------------------------------------------------------
__global__ __launch_bounds__(512) void out_ln_mfma_kernel(
    const u16* __restrict__ accbf, const float* __restrict__ x,
    const u16* __restrict__ WoT, const float* __restrict__ bo,
    const float* __restrict__ gamma, const float* __restrict__ beta,
    float* __restrict__ out) {
  __shared__ u16 as_[2][64 * 64];     // 2 x 8 KB
  __shared__ u16 bs_[2][512 * 64];    // 2 x 64 KB
  __shared__ float red[64][4][2];     // 2 KB
  const int tid = threadIdx.x, w = tid >> 6, l = tid & 63;
  const int r0 = blockIdx.x * 64;
  const int wr = w >> 2, wc = w & 3;

  f32x4 acc[2][8];
#pragma unroll
  for (int mm = 0; mm < 2; ++mm)
#pragma unroll
    for (int n = 0; n < 8; ++n) acc[mm][n] = (f32x4){0.f,0.f,0.f,0.f};

  auto stageA = [&](int c, int buf) {
    int row = 8 * w + (l >> 3);
    int ss = (l & 7) ^ (row & 7);
    gload16(accbf + ((size_t)(r0 + row) * Dn + c * 64 + ss * 8),
            (char*)&as_[buf][0] + w * 1024);
  };
  auto stageB = [&](int c, int buf) {
#pragma unroll
    for (int ii = 0; ii < 8; ++ii) {
      int i = 8 * w + ii;
      int n = i * 8 + (l >> 3);
      int ss = (l & 7) ^ (n & 7);
      gload16(WoT + ((size_t)n * Dn + c * 64 + ss * 8),
              (char*)&bs_[buf][0] + i * 1024);
    }
  };
  stageA(0, 0); stageB(0, 0);
  __syncthreads();
  for (int c = 0; c < 8; ++c) {
    if (c + 1 < 8) { stageA(c + 1, (c + 1) & 1); stageB(c + 1, (c + 1) & 1); }
    const u16* ab = &as_[c & 1][0];
    const u16* bb = &bs_[c & 1][0];
#pragma unroll
    for (int kk = 0; kk < 2; ++kk) {
      int rA0 = wr * 32 + (l & 15);
      int sA = ((l >> 4) + 4 * kk) ^ (rA0 & 7);
      bf16x8 a0 = *(const bf16x8*)(ab + rA0 * 64 + sA * 8);
      bf16x8 a1 = *(const bf16x8*)(ab + (rA0 + 16) * 64 + sA * 8);
#pragma unroll
      for (int n = 0; n < 8; ++n) {
        int rB = wc * 128 + n * 16 + (l & 15);
        int sB = ((l >> 4) + 4 * kk) ^ (rB & 7);
        bf16x8 bv = *(const bf16x8*)(bb + rB * 64 + sB * 8);
        acc[0][n] = mfma16(a0, bv, acc[0][n]);
        acc[1][n] = mfma16(a1, bv, acc[1][n]);
      }
    }
    __syncthreads();
  }

  // epilogue: bias + residual, then LayerNorm
  float g_[8], be_[8], bo_[8];
#pragma unroll
  for (int n = 0; n < 8; ++n) {
    int col = wc * 128 + n * 16 + (l & 15);
    bo_[n] = bo[col]; g_[n] = gamma[col]; be_[n] = beta[col];
  }
#pragma unroll
  for (int mm = 0; mm < 2; ++mm)
#pragma unroll
    for (int i = 0; i < 4; ++i) {
      int row = r0 + wr * 32 + mm * 16 + 4 * (l >> 4) + i;
#pragma unroll
      for (int n = 0; n < 8; ++n) {
        int col = wc * 128 + n * 16 + (l & 15);
        acc[mm][n][i] += bo_[n] + x[(size_t)row * Dn + col];
      }
    }
#pragma unroll
  for (int mm = 0; mm < 2; ++mm)
#pragma unroll
    for (int i = 0; i < 4; ++i) {
      float s = 0.f, s2 = 0.f;
#pragma unroll
      for (int n = 0; n < 8; ++n) { float v = acc[mm][n][i]; s += v; s2 += v * v; }
#pragma unroll
      for (int o = 8; o; o >>= 1) { s += __shfl_xor(s, o); s2 += __shfl_xor(s2, o); }
      if ((l & 15) == 0) {
        int rl = wr * 32 + mm * 16 + 4 * (l >> 4) + i;
        red[rl][wc][0] = s; red[rl][wc][1] = s2;
      }
    }
  __syncthreads();
#pragma unroll
  for (int mm = 0; mm < 2; ++mm)
#pragma unroll
    for (int i = 0; i < 4; ++i) {
      int rl = wr * 32 + mm * 16 + 4 * (l >> 4) + i;
      float s  = red[rl][0][0] + red[rl][1][0] + red[rl][2][0] + red[rl][3][0];
      float s2 = red[rl][0][1] + red[rl][1][1] + red[rl][2][1] + red[rl][3][1];
      float mean = s * (1.f / 512.f);
      float var  = s2 * (1.f / 512.f) - mean * mean;
      float inv  = rsqrtf(var + 1e-5f);
      int row = r0 + rl;
#pragma unroll
      for (int n = 0; n < 8; ++n) {
        int col = wc * 128 + n * 16 + (l & 15);
        out[(size_t)row * Dn + col] = (acc[mm][n][i] - mean) * inv * g_[n] + be_[n];
      }
    }
}

// ---------------------------------------------------------------------------
extern "C" void kernel_launch(void* const* d_in, const int* in_sizes, int n_in,
                              void* d_out, int out_size, void* d_ws, size_t ws_size,
                              hipStream_t stream) {
  const float* x     = (const float*)d_in[0];
  const float* Wq    = (const float*)d_in[1];
  const float* bq    = (const float*)d_in[2];
  const float* Wk    = (const float*)d_in[3];
  const float* bk    = (const float*)d_in[4];
  const float* Wo    = (const float*)d_in[5];
  const float* bo    = (const float*)d_in[6];
  const float* gamma = (const float*)d_in[7];
  const float* beta  = (const float*)d_in[8];
  float* out = (float*)d_out;

  // workspace (u16 elems)
  u16* qbf   = (u16*)d_ws;
  u16* kbf   = qbf   + (size_t)Bn * Tn * DKn;          // +2,097,152
  u16* xT    = kbf   + (size_t)Bn * Tn * DKn;          // +2,097,152
  u16* xbf   = xT    + (size_t)Bn * Dn * Tn;           // +8,388,608
  u16* Wg    = xbf   + (size_t)Bn * Tn * Dn;           // +8,388,608
  u16* accbf = Wg    + (size_t)Bn * 32 * QB * WJ;      // +13,631,488
  u16* WqkT  = accbf + (size_t)Bn * Tn * Dn;           // +8,388,608
  u16* WoT   = WqkT  + (size_t)256 * 512;              // +131,072

  xpose_kernel<<<Bn * 256, 256, 0, stream>>>(x, xT, xbf);
  wprep_kernel<<<96, 256, 0, stream>>>(Wq, Wk, Wo, WqkT, WoT);
  qk_mfma_kernel<<<Bn * Tn / 64, 512, 0, stream>>>(xbf, WqkT, bq, bk, qbf, kbf);
  weights_kernel<<<Bn * 64, 512, 0, stream>>>(qbf, kbf, Wg);
  pv_kernel<<<Bn * 32, 512, 0, stream>>>(Wg, xT, accbf);
  out_ln_mfma_kernel<<<Bn * Tn / 64, 512, 0, stream>>>(accbf, x, WoT, bo, gamma, beta, out);
}

// Round 5
// 136.819 us; speedup vs baseline: 8.3711x; 1.0757x over previous
//
#include <hip/hip_runtime.h>

typedef unsigned short u16;
typedef __attribute__((ext_vector_type(4))) unsigned short u16x4;
typedef __attribute__((ext_vector_type(8))) unsigned short u16x8;
typedef __attribute__((ext_vector_type(8))) short bf16x8;
typedef __attribute__((ext_vector_type(4))) float f32x4;

constexpr int Bn = 8, Tn = 2048, Dn = 512, DKn = 128;
constexpr int QB = 64;      // query rows per pv block
constexpr int WJ = 832;     // padded union window for pv = 13*64
constexpr int NCH = 13;     // pv K-chunks of 64
constexpr int WQB = 16;     // query rows per weights block
constexpr int WST = 776;    // weights S LDS stride (u16): covers jj<768, 2-way-free banks

__device__ inline u16 f2bf(float f) {
  unsigned u = __float_as_uint(f);
  return (u16)((u + 0x7FFFu + ((u >> 16) & 1u)) >> 16);
}
__device__ inline float bf2f(u16 h) {
  return __uint_as_float(((unsigned)h) << 16);
}
__device__ inline void gload16(const void* g, void* l) {
  __builtin_amdgcn_global_load_lds(
      (const __attribute__((address_space(1))) unsigned int*)g,
      (__attribute__((address_space(3))) unsigned int*)l, 16, 0, 0);
}
__device__ inline f32x4 mfma16(bf16x8 a, bf16x8 b, f32x4 c) {
  return __builtin_amdgcn_mfma_f32_16x16x32_bf16(a, b, c, 0, 0, 0);
}

// ---------------------------------------------------------------------------
// Kernel 1: xT[b][d][t] = bf16(x[b][t][d]) AND xbf[b][t][d] = bf16(x[b][t][d]).
// ---------------------------------------------------------------------------
__global__ __launch_bounds__(256) void xpose_kernel(
    const float* __restrict__ x, u16* __restrict__ xT, u16* __restrict__ xbf) {
  __shared__ u16 tile[64][72];
  const int blk = blockIdx.x;
  const int b = blk >> 8;                 // 256 tiles per batch
  const int rem = blk & 255;
  const int t0 = (rem >> 3) * 64, d0 = (rem & 7) * 64;
  const int tid = threadIdx.x;

#pragma unroll
  for (int it = 0; it < 4; ++it) {
    int r = (tid >> 4) + it * 16;
    int c = (tid & 15) * 4;
    float4 v = *(const float4*)&x[(size_t)(b * Tn + t0 + r) * Dn + d0 + c];
    u16 b0 = f2bf(v.x), b1 = f2bf(v.y), b2 = f2bf(v.z), b3 = f2bf(v.w);
    tile[c + 0][r] = b0;
    tile[c + 1][r] = b1;
    tile[c + 2][r] = b2;
    tile[c + 3][r] = b3;
    u16x4 pv; pv[0] = b0; pv[1] = b1; pv[2] = b2; pv[3] = b3;
    *(u16x4*)&xbf[(size_t)(b * Tn + t0 + r) * Dn + d0 + c] = pv;
  }
  __syncthreads();
  const int dr = tid >> 2, ts = (tid & 3) * 16;
  u16x8 v0 = *(const u16x8*)&tile[dr][ts];
  u16x8 v1 = *(const u16x8*)&tile[dr][ts + 8];
  u16* dst = xT + (size_t)(b * Dn + d0 + dr) * Tn + t0 + ts;
  *(u16x8*)dst = v0;
  *(u16x8*)(dst + 8) = v1;
}

// ---------------------------------------------------------------------------
// Kernel 2: weight prep.  WqkT[n][d] = bf16(Wq|Wk[d][n]) (n<128 -> Wq),
//           WoT[n][d] = bf16(Wo[d][n]).
// ---------------------------------------------------------------------------
__global__ __launch_bounds__(256) void wprep_kernel(
    const float* __restrict__ Wq, const float* __restrict__ Wk,
    const float* __restrict__ Wo,
    u16* __restrict__ WqkT, u16* __restrict__ WoT) {
  __shared__ u16 tile[64][72];
  const int tid = threadIdx.x;
  const int blk = blockIdx.x;
  const float* src; u16* dst;
  int srcC, r0, c0, rowOff;
  if (blk < 32) {
    src = (blk < 16) ? Wq : Wk;
    rowOff = (blk < 16) ? 0 : 128;
    int t = blk & 15;
    r0 = (t >> 1) * 64; c0 = (t & 1) * 64;
    srcC = 128; dst = WqkT;
  } else {
    int t = blk - 32;
    src = Wo; rowOff = 0;
    r0 = (t >> 3) * 64; c0 = (t & 7) * 64;
    srcC = 512; dst = WoT;
  }
#pragma unroll
  for (int it = 0; it < 4; ++it) {
    int r = (tid >> 4) + it * 16;
    int c = (tid & 15) * 4;
    float4 v = *(const float4*)&src[(size_t)(r0 + r) * srcC + c0 + c];
    tile[c + 0][r] = f2bf(v.x);
    tile[c + 1][r] = f2bf(v.y);
    tile[c + 2][r] = f2bf(v.z);
    tile[c + 3][r] = f2bf(v.w);
  }
  __syncthreads();
  const int dr = tid >> 2, ts = (tid & 3) * 16;
  u16x8 v0 = *(const u16x8*)&tile[dr][ts];
  u16x8 v1 = *(const u16x8*)&tile[dr][ts + 8];
  u16* dp = dst + (size_t)(rowOff + c0 + dr) * 512 + r0 + ts;
  *(u16x8*)dp = v0;
  *(u16x8*)(dp + 8) = v1;
}

// ---------------------------------------------------------------------------
// Kernel 3: q|k = xbf @ WqkT^T + bias, MFMA.  Block = 64 rows x 256 cols.
// ---------------------------------------------------------------------------
__global__ __launch_bounds__(512) void qk_mfma_kernel(
    const u16* __restrict__ xbf, const u16* __restrict__ WqkT,
    const float* __restrict__ bq, const float* __restrict__ bk,
    u16* __restrict__ qbf, u16* __restrict__ kbf) {
  __shared__ u16 as_[2][64 * 64];     // 2 x 8 KB
  __shared__ u16 bs_[2][256 * 64];    // 2 x 32 KB
  const int tid = threadIdx.x, w = tid >> 6, l = tid & 63;
  const int r0 = blockIdx.x * 64;
  const int wr = w >> 2, wc = w & 3;  // wave tile: 32 rows x 64 cols

  f32x4 acc[2][4];
#pragma unroll
  for (int mm = 0; mm < 2; ++mm)
#pragma unroll
    for (int n = 0; n < 4; ++n) acc[mm][n] = (f32x4){0.f, 0.f, 0.f, 0.f};

  auto stageA = [&](int c, int buf) {
    int row = 8 * w + (l >> 3);
    int ss = (l & 7) ^ (row & 7);
    gload16(xbf + ((size_t)(r0 + row) * Dn + c * 64 + ss * 8),
            (char*)&as_[buf][0] + w * 1024);
  };
  auto stageB = [&](int c, int buf) {
#pragma unroll
    for (int ii = 0; ii < 4; ++ii) {
      int i = 4 * w + ii;
      int n = i * 8 + (l >> 3);
      int ss = (l & 7) ^ (n & 7);
      gload16(WqkT + ((size_t)n * Dn + c * 64 + ss * 8),
              (char*)&bs_[buf][0] + i * 1024);
    }
  };
  stageA(0, 0); stageB(0, 0);
  __syncthreads();
  for (int c = 0; c < 8; ++c) {
    if (c + 1 < 8) { stageA(c + 1, (c + 1) & 1); stageB(c + 1, (c + 1) & 1); }
    const u16* ab = &as_[c & 1][0];
    const u16* bb = &bs_[c & 1][0];
#pragma unroll
    for (int kk = 0; kk < 2; ++kk) {
      int rA0 = wr * 32 + (l & 15);
      int sA = ((l >> 4) + 4 * kk) ^ (rA0 & 7);
      bf16x8 a0 = *(const bf16x8*)(ab + rA0 * 64 + sA * 8);
      bf16x8 a1 = *(const bf16x8*)(ab + (rA0 + 16) * 64 + sA * 8);
#pragma unroll
      for (int n = 0; n < 4; ++n) {
        int rB = wc * 64 + n * 16 + (l & 15);
        int sB = ((l >> 4) + 4 * kk) ^ (rB & 7);
        bf16x8 bv = *(const bf16x8*)(bb + rB * 64 + sB * 8);
        acc[0][n] = mfma16(a0, bv, acc[0][n]);
        acc[1][n] = mfma16(a1, bv, acc[1][n]);
      }
    }
    __syncthreads();
  }
#pragma unroll
  for (int n = 0; n < 4; ++n) {
    int col = wc * 64 + n * 16 + (l & 15);
    float bias = (col < 128) ? bq[col] : bk[col - 128];
    u16* outp = (col < 128) ? (qbf + col) : (kbf + col - 128);
#pragma unroll
    for (int mm = 0; mm < 2; ++mm)
#pragma unroll
      for (int i = 0; i < 4; ++i) {
        int row = r0 + wr * 32 + mm * 16 + 4 * (l >> 4) + i;
        outp[(size_t)row * DKn] = f2bf(acc[mm][n][i] + bias);
      }
  }
}

// ---------------------------------------------------------------------------
// Kernel 4: banded scores + 3-window softmax -> combined weights.
// Block = 16 query rows, 256 threads (4 waves = 4 j-quarters).  No max pass
// (scores are O(1); softmax w/o max-subtract is exact absent overflow).
// MFMA epilogue stores e = exp(s) to LDS (bf16) and accumulates ring sums
// in registers.  Final pass: 3 rcp -> F factors, scale stored e, u32 stores.
// Rings: ring0 d<=12, ring1 13..84, ring2 85..360.
// Writes pv tile layout: Wg[pvblk][64][832], zeros outside band/valid.
// ---------------------------------------------------------------------------
__global__ __launch_bounds__(256) void weights_kernel(
    const u16* __restrict__ qbf, const u16* __restrict__ kbf,
    u16* __restrict__ Wg) {
  __shared__ u16 S[WQB * WST];          // 24.8 KB bf16 e-values
  __shared__ float spart[4][WQB][3];    // 768 B ring-sum partials
  const int tid = threadIdx.x, w = tid >> 6, l = tid & 63;
  const int blk = blockIdx.x;           // Bn * 128 blocks
  const int b = blk >> 7;
  const int tt = blk & 127;
  const int t0 = tt * WQB;
  const int jbase = t0 - 360;
  const float scale = 0.08838834764831845f;   // 1/sqrt(128)

  // q fragments in registers (same 16 rows for all 4 waves)
  bf16x8 a[4];
  {
    int row = t0 + (l & 15);
    const u16* qp = qbf + (size_t)(b * Tn + row) * DKn + (l >> 4) * 8;
#pragma unroll
    for (int kk = 0; kk < 4; ++kk) a[kk] = *(const bf16x8*)(qp + kk * 32);
  }

  float s0[4], s1[4], s2[4];
#pragma unroll
  for (int i = 0; i < 4; ++i) { s0[i] = 0.f; s1[i] = 0.f; s2[i] = 0.f; }
  const int rbase = 4 * (l >> 4);

  // MFMA loop: 12 chunks of 64 j (wave w owns j-quarter w), no barriers
  for (int c = 0; c < 12; ++c) {
    int jj = c * 64 + w * 16 + (l & 15);
    int j = jbase + jj;
    int jc = j < 0 ? 0 : (j > Tn - 1 ? Tn - 1 : j);
    const u16* kp = kbf + (size_t)(b * Tn + jc) * DKn + (l >> 4) * 8;
    f32x4 acc = {0.f, 0.f, 0.f, 0.f};
#pragma unroll
    for (int kk = 0; kk < 4; ++kk)
      acc = mfma16(a[kk], *(const bf16x8*)(kp + kk * 32), acc);
    bool valid = (j >= 0) && (j < Tn);
#pragma unroll
    for (int i = 0; i < 4; ++i) {
      int r = rbase + i;
      int dist = jj - r - 360; dist = dist < 0 ? -dist : dist;
      float e = __expf(acc[i] * scale);
      e = (valid && dist <= 360) ? e : 0.f;
      S[r * WST + jj] = f2bf(e);
      bool in0 = dist <= 12, in1 = dist <= 84;
      s0[i] += in0 ? e : 0.f;
      s1[i] += (in1 && !in0) ? e : 0.f;
      s2[i] += in1 ? 0.f : e;
    }
  }

  // reduce ring sums over the 16 col-lanes, store per-wave partials
#pragma unroll
  for (int o = 1; o < 16; o <<= 1)
#pragma unroll
    for (int i = 0; i < 4; ++i) {
      s0[i] += __shfl_xor(s0[i], o);
      s1[i] += __shfl_xor(s1[i], o);
      s2[i] += __shfl_xor(s2[i], o);
    }
  if ((l & 15) == 0) {
#pragma unroll
    for (int i = 0; i < 4; ++i) {
      spart[w][rbase + i][0] = s0[i];
      spart[w][rbase + i][1] = s1[i];
      spart[w][rbase + i][2] = s2[i];
    }
  }
  __syncthreads();

  // combine & write.  Wave w owns rows 4w..4w+3.
  const int off = (tt & 3) * 16;            // row/col offset within pv tile
  const int pvblk = b * 32 + (tt >> 2);
#pragma unroll
  for (int rr = 0; rr < 4; ++rr) {
    int r = 4 * w + rr;
    float L0 = spart[0][r][0] + spart[1][r][0] + spart[2][r][0] + spart[3][r][0];
    float L1 = L0 + spart[0][r][1] + spart[1][r][1] + spart[2][r][1] + spart[3][r][1];
    float L2 = L1 + spart[0][r][2] + spart[1][r][2] + spart[2][r][2] + spart[3][r][2];
    float F2 = (1.f / 3.f) / L2;
    float F1 = (1.f / 3.f) / L1 + F2;
    float F0 = (1.f / 3.f) / L0 + F1;
    const int center = r + 360;
    u16* wrow = Wg + ((size_t)pvblk * QB + off + r) * WJ;
#pragma unroll
    for (int t = 0; t < 6; ++t) {
      int jjw = 2 * l + 128 * t;
      if (jjw < 736) {
        unsigned pv2 = *(const unsigned*)&S[r * WST + jjw];
        float e0 = bf2f((u16)(pv2 & 0xffff));
        float e1 = bf2f((u16)(pv2 >> 16));
        int d0 = jjw - center; d0 = d0 < 0 ? -d0 : d0;
        int d1 = jjw + 1 - center; d1 = d1 < 0 ? -d1 : d1;
        float c0 = e0 * (d0 <= 12 ? F0 : (d0 <= 84 ? F1 : F2));
        float c1 = e1 * (d1 <= 12 ? F0 : (d1 <= 84 ? F1 : F2));
        unsigned o2 = (unsigned)f2bf(c0) | ((unsigned)f2bf(c1) << 16);
        *(unsigned*)&wrow[off + jjw] = o2;
      }
    }
    // pad: zero pv columns [0,off) and [off+736, 832)
    if (l < 48) {
      int jjp = (l < (off >> 1)) ? 2 * l : 736 + 2 * l;
      *(unsigned*)&wrow[jjp] = 0u;
    }
  }
}

// ---------------------------------------------------------------------------
// Kernel 5: PV GEMM.  OUT[64 x 512] = Wg[64 x 832] @ xwin[832 x 512].
// ---------------------------------------------------------------------------
__global__ __launch_bounds__(512) void pv_kernel(
    const u16* __restrict__ Wg, const u16* __restrict__ xT,
    u16* __restrict__ accbf) {
  __shared__ u16 xs[2][Dn * 64];   // 2 x 64 KB
  __shared__ u16 ws[2][QB * 64];   // 2 x 8 KB
  const int tid = threadIdx.x;
  const int w = tid >> 6, l = tid & 63;
  const int blk = blockIdx.x;
  const int b = blk >> 5;
  const int t064 = (blk & 31) * QB;
  const int jbase = t064 - 360;
  const int wr = w >> 2, wc = w & 3;

  f32x4 acc[2][8];
#pragma unroll
  for (int mm = 0; mm < 2; ++mm)
#pragma unroll
    for (int n = 0; n < 8; ++n) acc[mm][n] = (f32x4){0.f,0.f,0.f,0.f};

  auto stage = [&](int c, int buf) {
    for (int ii = 0; ii < 8; ++ii) {
      int i = 8 * w + ii;
      int d = i * 8 + (l >> 3);
      int ss = (l & 7) ^ (d & 7);
      int g = jbase + c * 64 + ss * 8;
      g = g < 0 ? 0 : (g > Tn - 8 ? Tn - 8 : g);
      gload16(xT + ((size_t)(b * Dn + d) * Tn + g),
              (char*)&xs[buf][0] + i * 1024);
    }
    int row = 8 * w + (l >> 3);
    int ss = (l & 7) ^ (row & 7);
    gload16(Wg + ((size_t)(blk * QB + row)) * WJ + c * 64 + ss * 8,
            (char*)&ws[buf][0] + w * 1024);
  };

  stage(0, 0);
  __syncthreads();
  for (int c = 0; c < NCH; ++c) {
    if (c + 1 < NCH) stage(c + 1, (c + 1) & 1);
    const u16* xb = &xs[c & 1][0];
    const u16* wb = &ws[c & 1][0];
#pragma unroll
    for (int kk = 0; kk < 2; ++kk) {
      int rA0 = wr * 32 + (l & 15);
      int sA = ((l >> 4) + 4 * kk) ^ (rA0 & 7);
      bf16x8 a0 = *(const bf16x8*)(wb + rA0 * 64 + sA * 8);
      bf16x8 a1 = *(const bf16x8*)(wb + (rA0 + 16) * 64 + sA * 8);
#pragma unroll
      for (int n = 0; n < 8; ++n) {
        int rB = wc * 128 + n * 16 + (l & 15);
        int sB = ((l >> 4) + 4 * kk) ^ (rB & 7);
        bf16x8 bv = *(const bf16x8*)(xb + rB * 64 + sB * 8);
        acc[0][n] = mfma16(a0, bv, acc[0][n]);
        acc[1][n] = mfma16(a1, bv, acc[1][n]);
      }
    }
    __syncthreads();
  }
#pragma unroll
  for (int mm = 0; mm < 2; ++mm)
#pragma unroll
    for (int n = 0; n < 8; ++n)
#pragma unroll
      for (int i = 0; i < 4; ++i) {
        int row = wr * 32 + mm * 16 + 4 * (l >> 4) + i;
        int col = wc * 128 + n * 16 + (l & 15);
        accbf[(size_t)(b * Tn + t064 + row) * Dn + col] = f2bf(acc[mm][n][i]);
      }
}

// ---------------------------------------------------------------------------
// Kernel 6: OUT = LN(accbf @ WoT^T + bo + x) * gamma + beta, MFMA fused.
// ---------------------------------------------------------------------------
__global__ __launch_bounds__(512) void out_ln_mfma_kernel(
    const u16* __restrict__ accbf, const float* __restrict__ x,
    const u16* __restrict__ WoT, const float* __restrict__ bo,
    const float* __restrict__ gamma, const float* __restrict__ beta,
    float* __restrict__ out) {
  __shared__ u16 as_[2][64 * 64];     // 2 x 8 KB
  __shared__ u16 bs_[2][512 * 64];    // 2 x 64 KB
  __shared__ float red[64][4][2];     // 2 KB
  const int tid = threadIdx.x, w = tid >> 6, l = tid & 63;
  const int r0 = blockIdx.x * 64;
  const int wr = w >> 2, wc = w & 3;

  f32x4 acc[2][8];
#pragma unroll
  for (int mm = 0; mm < 2; ++mm)
#pragma unroll
    for (int n = 0; n < 8; ++n) acc[mm][n] = (f32x4){0.f,0.f,0.f,0.f};

  auto stageA = [&](int c, int buf) {
    int row = 8 * w + (l >> 3);
    int ss = (l & 7) ^ (row & 7);
    gload16(accbf + ((size_t)(r0 + row) * Dn + c * 64 + ss * 8),
            (char*)&as_[buf][0] + w * 1024);
  };
  auto stageB = [&](int c, int buf) {
#pragma unroll
    for (int ii = 0; ii < 8; ++ii) {
      int i = 8 * w + ii;
      int n = i * 8 + (l >> 3);
      int ss = (l & 7) ^ (n & 7);
      gload16(WoT + ((size_t)n * Dn + c * 64 + ss * 8),
              (char*)&bs_[buf][0] + i * 1024);
    }
  };
  stageA(0, 0); stageB(0, 0);
  __syncthreads();
  for (int c = 0; c < 8; ++c) {
    if (c + 1 < 8) { stageA(c + 1, (c + 1) & 1); stageB(c + 1, (c + 1) & 1); }
    const u16* ab = &as_[c & 1][0];
    const u16* bb = &bs_[c & 1][0];
#pragma unroll
    for (int kk = 0; kk < 2; ++kk) {
      int rA0 = wr * 32 + (l & 15);
      int sA = ((l >> 4) + 4 * kk) ^ (rA0 & 7);
      bf16x8 a0 = *(const bf16x8*)(ab + rA0 * 64 + sA * 8);
      bf16x8 a1 = *(const bf16x8*)(ab + (rA0 + 16) * 64 + sA * 8);
#pragma unroll
      for (int n = 0; n < 8; ++n) {
        int rB = wc * 128 + n * 16 + (l & 15);
        int sB = ((l >> 4) + 4 * kk) ^ (rB & 7);
        bf16x8 bv = *(const bf16x8*)(bb + rB * 64 + sB * 8);
        acc[0][n] = mfma16(a0, bv, acc[0][n]);
        acc[1][n] = mfma16(a1, bv, acc[1][n]);
      }
    }
    __syncthreads();
  }

  // epilogue: bias + residual, then LayerNorm
  float g_[8], be_[8], bo_[8];
#pragma unroll
  for (int n = 0; n < 8; ++n) {
    int col = wc * 128 + n * 16 + (l & 15);
    bo_[n] = bo[col]; g_[n] = gamma[col]; be_[n] = beta[col];
  }
#pragma unroll
  for (int mm = 0; mm < 2; ++mm)
#pragma unroll
    for (int i = 0; i < 4; ++i) {
      int row = r0 + wr * 32 + mm * 16 + 4 * (l >> 4) + i;
#pragma unroll
      for (int n = 0; n < 8; ++n) {
        int col = wc * 128 + n * 16 + (l & 15);
        acc[mm][n][i] += bo_[n] + x[(size_t)row * Dn + col];
      }
    }
#pragma unroll
  for (int mm = 0; mm < 2; ++mm)
#pragma unroll
    for (int i = 0; i < 4; ++i) {
      float s = 0.f, s2 = 0.f;
#pragma unroll
      for (int n = 0; n < 8; ++n) { float v = acc[mm][n][i]; s += v; s2 += v * v; }
#pragma unroll
      for (int o = 8; o; o >>= 1) { s += __shfl_xor(s, o); s2 += __shfl_xor(s2, o); }
      if ((l & 15) == 0) {
        int rl = wr * 32 + mm * 16 + 4 * (l >> 4) + i;
        red[rl][wc][0] = s; red[rl][wc][1] = s2;
      }
    }
  __syncthreads();
#pragma unroll
  for (int mm = 0; mm < 2; ++mm)
#pragma unroll
    for (int i = 0; i < 4; ++i) {
      int rl = wr * 32 + mm * 16 + 4 * (l >> 4) + i;
      float s  = red[rl][0][0] + red[rl][1][0] + red[rl][2][0] + red[rl][3][0];
      float s2 = red[rl][0][1] + red[rl][1][1] + red[rl][2][1] + red[rl][3][1];
      float mean = s * (1.f / 512.f);
      float var  = s2 * (1.f / 512.f) - mean * mean;
      float inv  = rsqrtf(var + 1e-5f);
      int row = r0 + rl;
#pragma unroll
      for (int n = 0; n < 8; ++n) {
        int col = wc * 128 + n * 16 + (l & 15);
        out[(size_t)row * Dn + col] = (acc[mm][n][i] - mean) * inv * g_[n] + be_[n];
      }
    }
}

// ---------------------------------------------------------------------------
extern "C" void kernel_launch(void* const* d_in, const int* in_sizes, int n_in,
                              void* d_out, int out_size, void* d_ws, size_t ws_size,
                              hipStream_t stream) {
  const float* x     = (const float*)d_in[0];
  const float* Wq    = (const float*)d_in[1];
  const float* bq    = (const float*)d_in[2];
  const float* Wk    = (const float*)d_in[3];
  const float* bk    = (const float*)d_in[4];
  const float* Wo    = (const float*)d_in[5];
  const float* bo    = (const float*)d_in[6];
  const float* gamma = (const float*)d_in[7];
  const float* beta  = (const float*)d_in[8];
  float* out = (float*)d_out;

  // workspace (u16 elems)
  u16* qbf   = (u16*)d_ws;
  u16* kbf   = qbf   + (size_t)Bn * Tn * DKn;          // +2,097,152
  u16* xT    = kbf   + (size_t)Bn * Tn * DKn;          // +2,097,152
  u16* xbf   = xT    + (size_t)Bn * Dn * Tn;           // +8,388,608
  u16* Wg    = xbf   + (size_t)Bn * Tn * Dn;           // +8,388,608
  u16* accbf = Wg    + (size_t)Bn * 32 * QB * WJ;      // +13,631,488
  u16* WqkT  = accbf + (size_t)Bn * Tn * Dn;           // +8,388,608
  u16* WoT   = WqkT  + (size_t)256 * 512;              // +131,072

  xpose_kernel<<<Bn * 256, 256, 0, stream>>>(x, xT, xbf);
  wprep_kernel<<<96, 256, 0, stream>>>(Wq, Wk, Wo, WqkT, WoT);
  qk_mfma_kernel<<<Bn * Tn / 64, 512, 0, stream>>>(xbf, WqkT, bq, bk, qbf, kbf);
  weights_kernel<<<Bn * 128, 256, 0, stream>>>(qbf, kbf, Wg);
  pv_kernel<<<Bn * 32, 512, 0, stream>>>(Wg, xT, accbf);
  out_ln_mfma_kernel<<<Bn * Tn / 64, 512, 0, stream>>>(accbf, x, WoT, bo, gamma, beta, out);
}

// Round 6
// 110.075 us; speedup vs baseline: 10.4050x; 1.2430x over previous
//
#include <hip/hip_runtime.h>

typedef unsigned short u16;
typedef __attribute__((ext_vector_type(4))) unsigned short u16x4;
typedef __attribute__((ext_vector_type(8))) unsigned short u16x8;
typedef __attribute__((ext_vector_type(8))) short bf16x8;
typedef __attribute__((ext_vector_type(4))) float f32x4;

constexpr int Bn = 8, Tn = 2048, Dn = 512, DKn = 128;
constexpr int QB = 64;      // query rows per pv tile
constexpr int WJ = 832;     // padded union window for pv = 13*64
constexpr int NCH = 13;     // pv K-chunks of 64
constexpr int WQB = 16;     // query rows per weights block
constexpr int WST = 776;    // weights S LDS stride (u16)

__device__ inline u16 f2bf(float f) {
  unsigned u = __float_as_uint(f);
  return (u16)((u + 0x7FFFu + ((u >> 16) & 1u)) >> 16);
}
__device__ inline float bf2f(u16 h) {
  return __uint_as_float(((unsigned)h) << 16);
}
__device__ inline void gload16(const void* g, void* l) {
  __builtin_amdgcn_global_load_lds(
      (const __attribute__((address_space(1))) unsigned int*)g,
      (__attribute__((address_space(3))) unsigned int*)l, 16, 0, 0);
}
__device__ inline f32x4 mfma16(bf16x8 a, bf16x8 b, f32x4 c) {
  return __builtin_amdgcn_mfma_f32_16x16x32_bf16(a, b, c, 0, 0, 0);
}

// ---------------------------------------------------------------------------
// Kernel 1: xT[b][d][t] = bf16(x[b][t][d]) AND xbf[b][t][d] = bf16(x[b][t][d]).
// ---------------------------------------------------------------------------
__global__ __launch_bounds__(256) void xpose_kernel(
    const float* __restrict__ x, u16* __restrict__ xT, u16* __restrict__ xbf) {
  __shared__ u16 tile[64][72];
  const int blk = blockIdx.x;
  const int b = blk >> 8;                 // 256 tiles per batch
  const int rem = blk & 255;
  const int t0 = (rem >> 3) * 64, d0 = (rem & 7) * 64;
  const int tid = threadIdx.x;

#pragma unroll
  for (int it = 0; it < 4; ++it) {
    int r = (tid >> 4) + it * 16;
    int c = (tid & 15) * 4;
    float4 v = *(const float4*)&x[(size_t)(b * Tn + t0 + r) * Dn + d0 + c];
    u16 b0 = f2bf(v.x), b1 = f2bf(v.y), b2 = f2bf(v.z), b3 = f2bf(v.w);
    tile[c + 0][r] = b0;
    tile[c + 1][r] = b1;
    tile[c + 2][r] = b2;
    tile[c + 3][r] = b3;
    u16x4 pv; pv[0] = b0; pv[1] = b1; pv[2] = b2; pv[3] = b3;
    *(u16x4*)&xbf[(size_t)(b * Tn + t0 + r) * Dn + d0 + c] = pv;
  }
  __syncthreads();
  const int dr = tid >> 2, ts = (tid & 3) * 16;
  u16x8 v0 = *(const u16x8*)&tile[dr][ts];
  u16x8 v1 = *(const u16x8*)&tile[dr][ts + 8];
  u16* dst = xT + (size_t)(b * Dn + d0 + dr) * Tn + t0 + ts;
  *(u16x8*)dst = v0;
  *(u16x8*)(dst + 8) = v1;
}

// ---------------------------------------------------------------------------
// Kernel 2: weight prep.  WqkT[n][d] = bf16(Wq|Wk[d][n]) (n<128 -> Wq),
//           WoT[n][d] = bf16(Wo[d][n]).
// ---------------------------------------------------------------------------
__global__ __launch_bounds__(256) void wprep_kernel(
    const float* __restrict__ Wq, const float* __restrict__ Wk,
    const float* __restrict__ Wo,
    u16* __restrict__ WqkT, u16* __restrict__ WoT) {
  __shared__ u16 tile[64][72];
  const int tid = threadIdx.x;
  const int blk = blockIdx.x;
  const float* src; u16* dst;
  int srcC, r0, c0, rowOff;
  if (blk < 32) {
    src = (blk < 16) ? Wq : Wk;
    rowOff = (blk < 16) ? 0 : 128;
    int t = blk & 15;
    r0 = (t >> 1) * 64; c0 = (t & 1) * 64;
    srcC = 128; dst = WqkT;
  } else {
    int t = blk - 32;
    src = Wo; rowOff = 0;
    r0 = (t >> 3) * 64; c0 = (t & 7) * 64;
    srcC = 512; dst = WoT;
  }
#pragma unroll
  for (int it = 0; it < 4; ++it) {
    int r = (tid >> 4) + it * 16;
    int c = (tid & 15) * 4;
    float4 v = *(const float4*)&src[(size_t)(r0 + r) * srcC + c0 + c];
    tile[c + 0][r] = f2bf(v.x);
    tile[c + 1][r] = f2bf(v.y);
    tile[c + 2][r] = f2bf(v.z);
    tile[c + 3][r] = f2bf(v.w);
  }
  __syncthreads();
  const int dr = tid >> 2, ts = (tid & 3) * 16;
  u16x8 v0 = *(const u16x8*)&tile[dr][ts];
  u16x8 v1 = *(const u16x8*)&tile[dr][ts + 8];
  u16* dp = dst + (size_t)(rowOff + c0 + dr) * 512 + r0 + ts;
  *(u16x8*)dp = v0;
  *(u16x8*)(dp + 8) = v1;
}

// ---------------------------------------------------------------------------
// Kernel 3: q|k = xbf @ WqkT^T + bias, MFMA.  Block = 64 rows x 256 cols.
// ---------------------------------------------------------------------------
__global__ __launch_bounds__(512) void qk_mfma_kernel(
    const u16* __restrict__ xbf, const u16* __restrict__ WqkT,
    const float* __restrict__ bq, const float* __restrict__ bk,
    u16* __restrict__ qbf, u16* __restrict__ kbf) {
  __shared__ u16 as_[2][64 * 64];     // 2 x 8 KB
  __shared__ u16 bs_[2][256 * 64];    // 2 x 32 KB
  const int tid = threadIdx.x, w = tid >> 6, l = tid & 63;
  const int r0 = blockIdx.x * 64;
  const int wr = w >> 2, wc = w & 3;  // wave tile: 32 rows x 64 cols

  f32x4 acc[2][4];
#pragma unroll
  for (int mm = 0; mm < 2; ++mm)
#pragma unroll
    for (int n = 0; n < 4; ++n) acc[mm][n] = (f32x4){0.f, 0.f, 0.f, 0.f};

  auto stageA = [&](int c, int buf) {
    int row = 8 * w + (l >> 3);
    int ss = (l & 7) ^ (row & 7);
    gload16(xbf + ((size_t)(r0 + row) * Dn + c * 64 + ss * 8),
            (char*)&as_[buf][0] + w * 1024);
  };
  auto stageB = [&](int c, int buf) {
#pragma unroll
    for (int ii = 0; ii < 4; ++ii) {
      int i = 4 * w + ii;
      int n = i * 8 + (l >> 3);
      int ss = (l & 7) ^ (n & 7);
      gload16(WqkT + ((size_t)n * Dn + c * 64 + ss * 8),
              (char*)&bs_[buf][0] + i * 1024);
    }
  };
  stageA(0, 0); stageB(0, 0);
  __syncthreads();
  for (int c = 0; c < 8; ++c) {
    if (c + 1 < 8) { stageA(c + 1, (c + 1) & 1); stageB(c + 1, (c + 1) & 1); }
    const u16* ab = &as_[c & 1][0];
    const u16* bb = &bs_[c & 1][0];
#pragma unroll
    for (int kk = 0; kk < 2; ++kk) {
      int rA0 = wr * 32 + (l & 15);
      int sA = ((l >> 4) + 4 * kk) ^ (rA0 & 7);
      bf16x8 a0 = *(const bf16x8*)(ab + rA0 * 64 + sA * 8);
      bf16x8 a1 = *(const bf16x8*)(ab + (rA0 + 16) * 64 + sA * 8);
#pragma unroll
      for (int n = 0; n < 4; ++n) {
        int rB = wc * 64 + n * 16 + (l & 15);
        int sB = ((l >> 4) + 4 * kk) ^ (rB & 7);
        bf16x8 bv = *(const bf16x8*)(bb + rB * 64 + sB * 8);
        acc[0][n] = mfma16(a0, bv, acc[0][n]);
        acc[1][n] = mfma16(a1, bv, acc[1][n]);
      }
    }
    __syncthreads();
  }
#pragma unroll
  for (int n = 0; n < 4; ++n) {
    int col = wc * 64 + n * 16 + (l & 15);
    float bias = (col < 128) ? bq[col] : bk[col - 128];
    u16* outp = (col < 128) ? (qbf + col) : (kbf + col - 128);
#pragma unroll
    for (int mm = 0; mm < 2; ++mm)
#pragma unroll
      for (int i = 0; i < 4; ++i) {
        int row = r0 + wr * 32 + mm * 16 + 4 * (l >> 4) + i;
        outp[(size_t)row * DKn] = f2bf(acc[mm][n][i] + bias);
      }
  }
}

// ---------------------------------------------------------------------------
// Kernel 4: banded scores + 3-window softmax -> combined weights.
// Block = 16 query rows, 256 threads.  XCD swizzle: one batch per XCD.
// ---------------------------------------------------------------------------
__global__ __launch_bounds__(256) void weights_kernel(
    const u16* __restrict__ qbf, const u16* __restrict__ kbf,
    u16* __restrict__ Wg) {
  __shared__ u16 S[WQB * WST];          // 24.8 KB bf16 e-values
  __shared__ float spart[4][WQB][3];    // 768 B ring-sum partials
  const int tid = threadIdx.x, w = tid >> 6, l = tid & 63;
  // XCD swizzle: 1024 blocks = 8 XCD x 128; XCD x owns batch x entirely.
  const int blk = (blockIdx.x & 7) * 128 + (blockIdx.x >> 3);
  const int b = blk >> 7;
  const int tt = blk & 127;
  const int t0 = tt * WQB;
  const int jbase = t0 - 360;
  const float scale = 0.08838834764831845f;   // 1/sqrt(128)

  // q fragments in registers (same 16 rows for all 4 waves)
  bf16x8 a[4];
  {
    int row = t0 + (l & 15);
    const u16* qp = qbf + (size_t)(b * Tn + row) * DKn + (l >> 4) * 8;
#pragma unroll
    for (int kk = 0; kk < 4; ++kk) a[kk] = *(const bf16x8*)(qp + kk * 32);
  }

  float s0[4], s1[4], s2[4];
#pragma unroll
  for (int i = 0; i < 4; ++i) { s0[i] = 0.f; s1[i] = 0.f; s2[i] = 0.f; }
  const int rbase = 4 * (l >> 4);

  // MFMA loop: 12 chunks of 64 j (wave w owns j-quarter w), no barriers
  for (int c = 0; c < 12; ++c) {
    int jj = c * 64 + w * 16 + (l & 15);
    int j = jbase + jj;
    int jc = j < 0 ? 0 : (j > Tn - 1 ? Tn - 1 : j);
    const u16* kp = kbf + (size_t)(b * Tn + jc) * DKn + (l >> 4) * 8;
    f32x4 acc = {0.f, 0.f, 0.f, 0.f};
#pragma unroll
    for (int kk = 0; kk < 4; ++kk)
      acc = mfma16(a[kk], *(const bf16x8*)(kp + kk * 32), acc);
    bool valid = (j >= 0) && (j < Tn);
#pragma unroll
    for (int i = 0; i < 4; ++i) {
      int r = rbase + i;
      int dist = jj - r - 360; dist = dist < 0 ? -dist : dist;
      float e = __expf(acc[i] * scale);
      e = (valid && dist <= 360) ? e : 0.f;
      S[r * WST + jj] = f2bf(e);
      bool in0 = dist <= 12, in1 = dist <= 84;
      s0[i] += in0 ? e : 0.f;
      s1[i] += (in1 && !in0) ? e : 0.f;
      s2[i] += in1 ? 0.f : e;
    }
  }

  // reduce ring sums over the 16 col-lanes, store per-wave partials
#pragma unroll
  for (int o = 1; o < 16; o <<= 1)
#pragma unroll
    for (int i = 0; i < 4; ++i) {
      s0[i] += __shfl_xor(s0[i], o);
      s1[i] += __shfl_xor(s1[i], o);
      s2[i] += __shfl_xor(s2[i], o);
    }
  if ((l & 15) == 0) {
#pragma unroll
    for (int i = 0; i < 4; ++i) {
      spart[w][rbase + i][0] = s0[i];
      spart[w][rbase + i][1] = s1[i];
      spart[w][rbase + i][2] = s2[i];
    }
  }
  __syncthreads();

  // combine & write.  Wave w owns rows 4w..4w+3.
  const int off = (tt & 3) * 16;            // row/col offset within pv tile
  const int pvblk = b * 32 + (tt >> 2);
#pragma unroll
  for (int rr = 0; rr < 4; ++rr) {
    int r = 4 * w + rr;
    float L0 = spart[0][r][0] + spart[1][r][0] + spart[2][r][0] + spart[3][r][0];
    float L1 = L0 + spart[0][r][1] + spart[1][r][1] + spart[2][r][1] + spart[3][r][1];
    float L2 = L1 + spart[0][r][2] + spart[1][r][2] + spart[2][r][2] + spart[3][r][2];
    float F2 = (1.f / 3.f) / L2;
    float F1 = (1.f / 3.f) / L1 + F2;
    float F0 = (1.f / 3.f) / L0 + F1;
    const int center = r + 360;
    u16* wrow = Wg + ((size_t)pvblk * QB + off + r) * WJ;
#pragma unroll
    for (int t = 0; t < 6; ++t) {
      int jjw = 2 * l + 128 * t;
      if (jjw < 736) {
        unsigned pv2 = *(const unsigned*)&S[r * WST + jjw];
        float e0 = bf2f((u16)(pv2 & 0xffff));
        float e1 = bf2f((u16)(pv2 >> 16));
        int d0 = jjw - center; d0 = d0 < 0 ? -d0 : d0;
        int d1 = jjw + 1 - center; d1 = d1 < 0 ? -d1 : d1;
        float c0 = e0 * (d0 <= 12 ? F0 : (d0 <= 84 ? F1 : F2));
        float c1 = e1 * (d1 <= 12 ? F0 : (d1 <= 84 ? F1 : F2));
        unsigned o2 = (unsigned)f2bf(c0) | ((unsigned)f2bf(c1) << 16);
        *(unsigned*)&wrow[off + jjw] = o2;
      }
    }
    // pad: zero pv columns [0,off) and [off+736, 832)
    if (l < 48) {
      int jjp = (l < (off >> 1)) ? 2 * l : 736 + 2 * l;
      *(unsigned*)&wrow[jjp] = 0u;
    }
  }
}

// ---------------------------------------------------------------------------
// Kernel 5: PV GEMM, split-D.  Block = 64 t x 256 d (half of D), KC=64.
// OUT[64 x 256] = Wg[64 x 832] @ xwin[832 x 256].  80 KB LDS -> 2 blocks/CU.
// XCD swizzle: 512 blocks = 8 XCD x 64; XCD x owns batch x (xT 2 MB L2-fit).
// ---------------------------------------------------------------------------
__global__ __launch_bounds__(512) void pv_kernel(
    const u16* __restrict__ Wg, const u16* __restrict__ xT,
    u16* __restrict__ accbf) {
  __shared__ u16 xs[2][256 * 64];  // 2 x 32 KB
  __shared__ u16 ws[2][QB * 64];   // 2 x 8 KB
  const int tid = threadIdx.x;
  const int w = tid >> 6, l = tid & 63;
  const int work = (blockIdx.x & 7) * 64 + (blockIdx.x >> 3);
  const int b = work >> 6;
  const int rem = work & 63;
  const int tt = rem >> 1;
  const int dh = rem & 1;          // which 256-col half of D
  const int t064 = tt * QB;
  const int jbase = t064 - 360;
  const int pvblk = b * 32 + tt;
  const int wr = w >> 2, wc = w & 3;   // wave tile: 32 t x 64 d

  f32x4 acc[2][4];
#pragma unroll
  for (int mm = 0; mm < 2; ++mm)
#pragma unroll
    for (int n = 0; n < 4; ++n) acc[mm][n] = (f32x4){0.f,0.f,0.f,0.f};

  auto stage = [&](int c, int buf) {
#pragma unroll
    for (int ii = 0; ii < 4; ++ii) {
      int i = 4 * w + ii;
      int d = i * 8 + (l >> 3);          // 0..255 local d row
      int ss = (l & 7) ^ (d & 7);
      int g = jbase + c * 64 + ss * 8;
      g = g < 0 ? 0 : (g > Tn - 8 ? Tn - 8 : g);
      gload16(xT + ((size_t)(b * Dn + dh * 256 + d) * Tn + g),
              (char*)&xs[buf][0] + i * 1024);
    }
    int row = 8 * w + (l >> 3);
    int ss = (l & 7) ^ (row & 7);
    gload16(Wg + ((size_t)(pvblk * QB + row)) * WJ + c * 64 + ss * 8,
            (char*)&ws[buf][0] + w * 1024);
  };

  stage(0, 0);
  __syncthreads();
  for (int c = 0; c < NCH; ++c) {
    if (c + 1 < NCH) stage(c + 1, (c + 1) & 1);
    const u16* xb = &xs[c & 1][0];
    const u16* wb = &ws[c & 1][0];
#pragma unroll
    for (int kk = 0; kk < 2; ++kk) {
      int rA0 = wr * 32 + (l & 15);
      int sA = ((l >> 4) + 4 * kk) ^ (rA0 & 7);
      bf16x8 a0 = *(const bf16x8*)(wb + rA0 * 64 + sA * 8);
      bf16x8 a1 = *(const bf16x8*)(wb + (rA0 + 16) * 64 + sA * 8);
#pragma unroll
      for (int n = 0; n < 4; ++n) {
        int rB = wc * 64 + n * 16 + (l & 15);
        int sB = ((l >> 4) + 4 * kk) ^ (rB & 7);
        bf16x8 bv = *(const bf16x8*)(xb + rB * 64 + sB * 8);
        acc[0][n] = mfma16(a0, bv, acc[0][n]);
        acc[1][n] = mfma16(a1, bv, acc[1][n]);
      }
    }
    __syncthreads();
  }
#pragma unroll
  for (int mm = 0; mm < 2; ++mm)
#pragma unroll
    for (int n = 0; n < 4; ++n)
#pragma unroll
      for (int i = 0; i < 4; ++i) {
        int row = wr * 32 + mm * 16 + 4 * (l >> 4) + i;
        int col = dh * 256 + wc * 64 + n * 16 + (l & 15);
        accbf[(size_t)(b * Tn + t064 + row) * Dn + col] = f2bf(acc[mm][n][i]);
      }
}

// ---------------------------------------------------------------------------
// Kernel 6: OUT = LN(accbf @ WoT^T + bo + x) * gamma + beta, MFMA fused.
// ---------------------------------------------------------------------------
__global__ __launch_bounds__(512) void out_ln_mfma_kernel(
    const u16* __restrict__ accbf, const float* __restrict__ x,
    const u16* __restrict__ WoT, const float* __restrict__ bo,
    const float* __restrict__ gamma, const float* __restrict__ beta,
    float* __restrict__ out) {
  __shared__ u16 as_[2][64 * 64];     // 2 x 8 KB
  __shared__ u16 bs_[2][512 * 64];    // 2 x 64 KB
  __shared__ float red[64][4][2];     // 2 KB
  const int tid = threadIdx.x, w = tid >> 6, l = tid & 63;
  const int r0 = blockIdx.x * 64;
  const int wr = w >> 2, wc = w & 3;

  f32x4 acc[2][8];
#pragma unroll
  for (int mm = 0; mm < 2; ++mm)
#pragma unroll
    for (int n = 0; n < 8; ++n) acc[mm][n] = (f32x4){0.f,0.f,0.f,0.f};

  auto stageA = [&](int c, int buf) {
    int row = 8 * w + (l >> 3);
    int ss = (l & 7) ^ (row & 7);
    gload16(accbf + ((size_t)(r0 + row) * Dn + c * 64 + ss * 8),
            (char*)&as_[buf][0] + w * 1024);
  };
  auto stageB = [&](int c, int buf) {
#pragma unroll
    for (int ii = 0; ii < 8; ++ii) {
      int i = 8 * w + ii;
      int n = i * 8 + (l >> 3);
      int ss = (l & 7) ^ (n & 7);
      gload16(WoT + ((size_t)n * Dn + c * 64 + ss * 8),
              (char*)&bs_[buf][0] + i * 1024);
    }
  };
  stageA(0, 0); stageB(0, 0);
  __syncthreads();
  for (int c = 0; c < 8; ++c) {
    if (c + 1 < 8) { stageA(c + 1, (c + 1) & 1); stageB(c + 1, (c + 1) & 1); }
    const u16* ab = &as_[c & 1][0];
    const u16* bb = &bs_[c & 1][0];
#pragma unroll
    for (int kk = 0; kk < 2; ++kk) {
      int rA0 = wr * 32 + (l & 15);
      int sA = ((l >> 4) + 4 * kk) ^ (rA0 & 7);
      bf16x8 a0 = *(const bf16x8*)(ab + rA0 * 64 + sA * 8);
      bf16x8 a1 = *(const bf16x8*)(ab + (rA0 + 16) * 64 + sA * 8);
#pragma unroll
      for (int n = 0; n < 8; ++n) {
        int rB = wc * 128 + n * 16 + (l & 15);
        int sB = ((l >> 4) + 4 * kk) ^ (rB & 7);
        bf16x8 bv = *(const bf16x8*)(bb + rB * 64 + sB * 8);
        acc[0][n] = mfma16(a0, bv, acc[0][n]);
        acc[1][n] = mfma16(a1, bv, acc[1][n]);
      }
    }
    __syncthreads();
  }

  // epilogue: bias + residual, then LayerNorm
  float g_[8], be_[8], bo_[8];
#pragma unroll
  for (int n = 0; n < 8; ++n) {
    int col = wc * 128 + n * 16 + (l & 15);
    bo_[n] = bo[col]; g_[n] = gamma[col]; be_[n] = beta[col];
  }
#pragma unroll
  for (int mm = 0; mm < 2; ++mm)
#pragma unroll
    for (int i = 0; i < 4; ++i) {
      int row = r0 + wr * 32 + mm * 16 + 4 * (l >> 4) + i;
#pragma unroll
      for (int n = 0; n < 8; ++n) {
        int col = wc * 128 + n * 16 + (l & 15);
        acc[mm][n][i] += bo_[n] + x[(size_t)row * Dn + col];
      }
    }
#pragma unroll
  for (int mm = 0; mm < 2; ++mm)
#pragma unroll
    for (int i = 0; i < 4; ++i) {
      float s = 0.f, s2 = 0.f;
#pragma unroll
      for (int n = 0; n < 8; ++n) { float v = acc[mm][n][i]; s += v; s2 += v * v; }
#pragma unroll
      for (int o = 8; o; o >>= 1) { s += __shfl_xor(s, o); s2 += __shfl_xor(s2, o); }
      if ((l & 15) == 0) {
        int rl = wr * 32 + mm * 16 + 4 * (l >> 4) + i;
        red[rl][wc][0] = s; red[rl][wc][1] = s2;
      }
    }
  __syncthreads();
#pragma unroll
  for (int mm = 0; mm < 2; ++mm)
#pragma unroll
    for (int i = 0; i < 4; ++i) {
      int rl = wr * 32 + mm * 16 + 4 * (l >> 4) + i;
      float s  = red[rl][0][0] + red[rl][1][0] + red[rl][2][0] + red[rl][3][0];
      float s2 = red[rl][0][1] + red[rl][1][1] + red[rl][2][1] + red[rl][3][1];
      float mean = s * (1.f / 512.f);
      float var  = s2 * (1.f / 512.f) - mean * mean;
      float inv  = rsqrtf(var + 1e-5f);
      int row = r0 + rl;
#pragma unroll
      for (int n = 0; n < 8; ++n) {
        int col = wc * 128 + n * 16 + (l & 15);
        out[(size_t)row * Dn + col] = (acc[mm][n][i] - mean) * inv * g_[n] + be_[n];
      }
    }
}

// ---------------------------------------------------------------------------
extern "C" void kernel_launch(void* const* d_in, const int* in_sizes, int n_in,
                              void* d_out, int out_size, void* d_ws, size_t ws_size,
                              hipStream_t stream) {
  const float* x     = (const float*)d_in[0];
  const float* Wq    = (const float*)d_in[1];
  const float* bq    = (const float*)d_in[2];
  const float* Wk    = (const float*)d_in[3];
  const float* bk    = (const float*)d_in[4];
  const float* Wo    = (const float*)d_in[5];
  const float* bo    = (const float*)d_in[6];
  const float* gamma = (const float*)d_in[7];
  const float* beta  = (const float*)d_in[8];
  float* out = (float*)d_out;

  // workspace (u16 elems)
  u16* qbf   = (u16*)d_ws;
  u16* kbf   = qbf   + (size_t)Bn * Tn * DKn;          // +2,097,152
  u16* xT    = kbf   + (size_t)Bn * Tn * DKn;          // +2,097,152
  u16* xbf   = xT    + (size_t)Bn * Dn * Tn;           // +8,388,608
  u16* Wg    = xbf   + (size_t)Bn * Tn * Dn;           // +8,388,608
  u16* accbf = Wg    + (size_t)Bn * 32 * QB * WJ;      // +13,631,488
  u16* WqkT  = accbf + (size_t)Bn * Tn * Dn;           // +8,388,608
  u16* WoT   = WqkT  + (size_t)256 * 512;              // +131,072

  xpose_kernel<<<Bn * 256, 256, 0, stream>>>(x, xT, xbf);
  wprep_kernel<<<96, 256, 0, stream>>>(Wq, Wk, Wo, WqkT, WoT);
  qk_mfma_kernel<<<Bn * Tn / 64, 512, 0, stream>>>(xbf, WqkT, bq, bk, qbf, kbf);
  weights_kernel<<<Bn * 128, 256, 0, stream>>>(qbf, kbf, Wg);
  pv_kernel<<<Bn * 64, 512, 0, stream>>>(Wg, xT, accbf);
  out_ln_mfma_kernel<<<Bn * Tn / 64, 512, 0, stream>>>(accbf, x, WoT, bo, gamma, beta, out);
}